// Round 2
// baseline (569.791 us; speedup 1.0000x reference)
//
#include <hip/hip_runtime.h>
#include <math.h>

#define NW 960
#define NT 144
#define DIM 192
#define NH 6
#define HD 32
#define WCOLS 576

typedef __bf16 bf16x8 __attribute__((ext_vector_type(8)));
typedef float floatx4 __attribute__((ext_vector_type(4)));

__device__ __forceinline__ unsigned short f2bf(float x) {
    union { float f; unsigned u; } v; v.f = x;
    unsigned r = v.u + 0x7fffu + ((v.u >> 16) & 1u);
    return (unsigned short)(r >> 16);
}
__device__ __forceinline__ float bf2f(unsigned short b) {
    union { unsigned u; float f; } v; v.u = ((unsigned)b) << 16;
    return v.f;
}
__device__ __forceinline__ floatx4 mfma16(bf16x8 a, bf16x8 b, floatx4 c) {
    return __builtin_amdgcn_mfma_f32_16x16x32_bf16(a, b, c, 0, 0, 0);
}
// Aliasing-safe LDS vector load: used where a bf16x8 read must not be
// reordered above preceding unsigned-short stores to the same region
// (TBAA would otherwise allow the hoist - the P tile is the only LDS
// RAW seam not protected by __syncthreads()).
__device__ __forceinline__ bf16x8 lds_ld8(const unsigned short* p) {
    bf16x8 v;
    __builtin_memcpy(&v, p, 16);
    return v;
}

// ===========================================================================
// Prep kernels (tiny; weights + bias only)
// ===========================================================================
__global__ void prep_bias(const int* __restrict__ rel_index,
                          const float* __restrict__ bias_table,
                          float* __restrict__ bias_pre) {
    int i = blockIdx.x * 256 + threadIdx.x;           // [6][144][144]
    if (i < NH * NT * NT) {
        int h = i / (NT * NT);
        int rem = i - h * (NT * NT);
        bias_pre[i] = bias_table[rel_index[rem] * NH + h];
    }
}

// wq frag: [h][j(6)][kt(6)][lane(64)][pos(8)]
__global__ void prep_wq_frag(const float* __restrict__ w_qkv,
                             unsigned short* __restrict__ wh,
                             unsigned short* __restrict__ wl) {
    int i = blockIdx.x * 256 + threadIdx.x;           // 6*6*6*512 = 110592
    if (i < NH * 6 * 6 * 512) {
        int h = i / 18432; int r = i - h * 18432;
        int j = r / 3072;  r -= j * 3072;
        int kt = r / 512;  r -= kt * 512;
        int lane = r >> 3, pos = r & 7;
        int col96 = j * 16 + (lane & 15);
        int k = kt * 32 + (lane >> 4) * 8 + pos;
        float v = w_qkv[k * WCOLS + (col96 >> 5) * DIM + h * HD + (col96 & 31)];
        unsigned short hi = f2bf(v);
        wh[i] = hi;
        wl[i] = f2bf(v - bf2f(hi));
    }
}

// wout frag: [nt(12)][kt(6)][lane(64)][pos(8)]
__global__ void prep_wo_frag(const float* __restrict__ w_out,
                             unsigned short* __restrict__ wh,
                             unsigned short* __restrict__ wl) {
    int i = blockIdx.x * 256 + threadIdx.x;           // 12*6*512 = 36864
    if (i < 12 * 6 * 512) {
        int nt = i / 3072; int r = i - nt * 3072;
        int kt = r / 512;  r -= kt * 512;
        int lane = r >> 3, pos = r & 7;
        int ocol = nt * 16 + (lane & 15);
        int k = kt * 32 + (lane >> 4) * 8 + pos;
        float v = w_out[k * DIM + ocol];
        unsigned short hi = f2bf(v);
        wh[i] = hi;
        wl[i] = f2bf(v - bf2f(hi));
    }
}

// ===========================================================================
// Fused: QKV + attention (6 heads) + out-proj, one block per window.
// 384 threads (6 waves). LDS (shorts, total 73120 = 146240 B):
//   XF [kt6][tile9][512] @0      (27648)  -- x bf16 A-frags; reused as O-frags
//   Q2 [hl2][tile9][512] @27648  (9216)
//   K2 [hl2][tile9][512] @36864  (9216)
//   V2t[4][slab5][512]   @46080  (10240)  -- (hl*2+ntv) groups
//   P  [wv6][slab5][512] @56320  (15360)
//   MB [144][5] u32      @71680  (1440 sh)
// ===========================================================================
__global__ __launch_bounds__(384, 2)
void fused(const float* __restrict__ x, const int* __restrict__ mask,
           const float* __restrict__ bias_pre,
           const unsigned short* __restrict__ wqh, const unsigned short* __restrict__ wql,
           const float* __restrict__ b_qkv,
           const unsigned short* __restrict__ woh_g, const unsigned short* __restrict__ wol_g,
           const float* __restrict__ b_out, float* __restrict__ out)
{
    __shared__ __align__(16) unsigned short lds[73120];
    const int XFo = 0, Q2o = 27648, K2o = 36864, V2o = 46080, Po = 56320, MBo = 71680;

    const int t = threadIdx.x;
    const int w = blockIdx.x;
    const int lane = t & 63, wv = t >> 6;
    const int c = lane & 15, q = lane >> 4;
    const float scale = 0.17677669529663687f;
    const float* xg = x + (size_t)w * NT * DIM;

    // ---- stage x -> XF bf16 A-frags (13824 dwords) ----
    {
        unsigned* XFd = (unsigned*)&lds[XFo];
        #pragma unroll
        for (int l = 0; l < 36; ++l) {
            int d = t + l * 384;
            int kt = d / 2304; int r2 = d - kt * 2304;
            int tile = r2 >> 8; int r3 = r2 & 255;
            int ln = r3 >> 2, pp = r3 & 3;
            int n = tile * 16 + (ln & 15);
            int k = kt * 32 + (ln >> 4) * 8 + pp * 2;
            float2 xv = *(const float2*)&xg[n * DIM + k];
            XFd[d] = (unsigned)f2bf(xv.x) | ((unsigned)f2bf(xv.y) << 16);
        }
    }
    // ---- zero pads: V2t tokens 144..159, P k 144..159 ----
    for (int e = t; e < 2560; e += 384) {
        if (e < 1024) {
            int gi = e >> 8, l2 = 32 + ((e >> 3) & 31), pos = e & 7;
            lds[V2o + (gi * 5 + 4) * 512 + l2 * 8 + pos] = 0;
        } else {
            int e2 = e - 1024;
            int wvi = e2 >> 8, l2 = 32 + ((e2 >> 3) & 31), pos = e2 & 7;
            lds[Po + (wvi * 5 + 4) * 512 + l2 * 8 + pos] = 0;
        }
    }
    // ---- mask -> bit-packed MB via ballot (coalesced, read once per window) ----
    {
        unsigned* mb = (unsigned*)&lds[MBo];
        for (int rr = 0; rr < 24; ++rr) {
            int n = wv * 24 + rr;
            const int* mrow = mask + ((size_t)w * NT + n) * NT;
            unsigned long long b0 = __ballot(mrow[lane] != 0);
            unsigned long long b1 = __ballot(mrow[64 + lane] != 0);
            int mv = (lane < 16) ? mrow[128 + lane] : 0;
            unsigned long long b2 = __ballot(mv != 0);
            if (lane == 0) {
                mb[n * 5 + 0] = (unsigned)b0;
                mb[n * 5 + 1] = (unsigned)(b0 >> 32);
                mb[n * 5 + 2] = (unsigned)b1;
                mb[n * 5 + 3] = (unsigned)(b1 >> 32);
                mb[n * 5 + 4] = (unsigned)b2;
            }
        }
    }

    const int part = wv % 3;        // phase-A role: 0=Q,1=K,2=V columns
    const int hlA  = wv / 3;        // phase-A head-in-group
    const int j0   = part * 2;
    const int hlB  = wv & 1;        // phase-B head-in-group
    const int s0   = wv >> 1;       // phase-B base strip

    floatx4 Oacc[3][3][2];

    #pragma unroll
    for (int g = 0; g < 3; ++g) {
        __syncthreads();            // XF/MB ready (g=0) / prev group's B reads done
        const int hg = 2 * g + hlA;

        // hoisted hi B-frags for this wave's 2 column-tiles
        const unsigned short* bh0p = wqh + (size_t)((hg * 6 + j0) * 6) * 512 + lane * 8;
        const unsigned short* bh1p = wqh + (size_t)((hg * 6 + j0 + 1) * 6) * 512 + lane * 8;
        const unsigned short* bl0p = wql + (size_t)((hg * 6 + j0) * 6) * 512 + lane * 8;
        const unsigned short* bl1p = wql + (size_t)((hg * 6 + j0 + 1) * 6) * 512 + lane * 8;
        bf16x8 bh0[6], bh1[6];
        #pragma unroll
        for (int kt = 0; kt < 6; ++kt) {
            bh0[kt] = *(const bf16x8*)&bh0p[kt * 512];
            bh1[kt] = *(const bf16x8*)&bh1p[kt * 512];
        }
        float bq0 = b_qkv[part * DIM + hg * HD + c];
        float bq1 = b_qkv[part * DIM + hg * HD + 16 + c];

        // ---- QKV gemm for this group's 2 column-tiles of this wave ----
        #pragma unroll
        for (int i3 = 0; i3 < 3; ++i3) {
            floatx4 a[3][2];
            #pragma unroll
            for (int ii = 0; ii < 3; ++ii) { a[ii][0] = (floatx4)0.0f; a[ii][1] = (floatx4)0.0f; }
            #pragma unroll
            for (int kt = 0; kt < 6; ++kt) {
                bf16x8 bl0 = *(const bf16x8*)&bl0p[kt * 512];
                bf16x8 bl1 = *(const bf16x8*)&bl1p[kt * 512];
                #pragma unroll
                for (int ii = 0; ii < 3; ++ii) {
                    bf16x8 ah = *(const bf16x8*)&lds[XFo + (kt * 9 + i3 * 3 + ii) * 512 + lane * 8];
                    a[ii][0] = mfma16(ah, bh0[kt], a[ii][0]);
                    a[ii][0] = mfma16(ah, bl0, a[ii][0]);
                    a[ii][1] = mfma16(ah, bh1[kt], a[ii][1]);
                    a[ii][1] = mfma16(ah, bl1, a[ii][1]);
                }
            }
            // scatter C-layout -> frag layouts (verified formulas from R3)
            #pragma unroll
            for (int ii = 0; ii < 3; ++ii) {
                int i = i3 * 3 + ii;
                #pragma unroll
                for (int r = 0; r < 4; ++r) {
                    float v0 = a[ii][0][r] + bq0;
                    float v1 = a[ii][1][r] + bq1;
                    if (part == 0) {
                        lds[Q2o + (hlA * 9 + i) * 512 + ((q * 4 + r) + 16 * (c >> 3)) * 8 + (c & 7)] = f2bf(v0 * scale);
                        lds[Q2o + (hlA * 9 + i) * 512 + ((q * 4 + r) + 16 * (2 + (c >> 3))) * 8 + (c & 7)] = f2bf(v1 * scale);
                    } else if (part == 1) {
                        lds[K2o + (hlA * 9 + i) * 512 + ((q * 4 + r) + 16 * (c >> 3)) * 8 + (c & 7)] = f2bf(v0);
                        lds[K2o + (hlA * 9 + i) * 512 + ((q * 4 + r) + 16 * (2 + (c >> 3))) * 8 + (c & 7)] = f2bf(v1);
                    } else {
                        int n = i * 16 + q * 4 + r;
                        lds[V2o + ((hlA * 2 + 0) * 5 + (n >> 5)) * 512 + (c + 16 * ((n >> 3) & 3)) * 8 + (n & 7)] = f2bf(v0);
                        lds[V2o + ((hlA * 2 + 1) * 5 + (n >> 5)) * 512 + (c + 16 * ((n >> 3) & 3)) * 8 + (n & 7)] = f2bf(v1);
                    }
                }
            }
        }
        __syncthreads();

        // ---- attention: 3 units/wave (even split), barrier-free ----
        const int hB = 2 * g + hlB;
        #pragma unroll
        for (int it = 0; it < 3; ++it) {
            int s = s0 + 3 * it;
            bf16x8 qf = *(const bf16x8*)&lds[Q2o + (hlB * 9 + s) * 512 + lane * 8];
            floatx4 sacc[9];
            #pragma unroll
            for (int nt = 0; nt < 9; ++nt) {
                bf16x8 kf = *(const bf16x8*)&lds[K2o + (hlB * 9 + nt) * 512 + lane * 8];
                sacc[nt] = mfma16(qf, kf, (floatx4)0.0f);
            }
            const unsigned* mb = (const unsigned*)&lds[MBo];
            #pragma unroll
            for (int r = 0; r < 4; ++r) {
                int n = s * 16 + q * 4 + r;
                const float* brow = bias_pre + hB * (NT * NT) + n * NT;
                unsigned mwv[5];
                #pragma unroll
                for (int k5 = 0; k5 < 5; ++k5) mwv[k5] = mb[n * 5 + k5];
                float e[9]; float mx = -1e30f;
                #pragma unroll
                for (int nt = 0; nt < 9; ++nt) {
                    float val = sacc[nt][r] + brow[nt * 16 + c];
                    unsigned bit = (mwv[nt >> 1] >> (((nt & 1) << 4) + c)) & 1u;
                    val = bit ? val : -1e9f;
                    e[nt] = val; mx = fmaxf(mx, val);
                }
                #pragma unroll
                for (int o = 8; o; o >>= 1) mx = fmaxf(mx, __shfl_xor(mx, o, 64));
                float sum = 0.f;
                #pragma unroll
                for (int nt = 0; nt < 9; ++nt) { e[nt] = __expf(e[nt] - mx); sum += e[nt]; }
                #pragma unroll
                for (int o = 8; o; o >>= 1) sum += __shfl_xor(sum, o, 64);
                float rinv = 1.0f / sum;
                #pragma unroll
                for (int nt = 0; nt < 9; ++nt) {
                    int col = nt * 16 + c;
                    lds[Po + (wv * 5 + (col >> 5)) * 512 +
                        ((q * 4 + r) + 16 * ((col >> 3) & 3)) * 8 + (col & 7)] = f2bf(e[nt] * rinv);
                }
            }
            // Compiler memory fence: the P-tile stores above and the P-frag
            // loads below alias through different types (unsigned short vs
            // __bf16 vector); hardware DS is in-order per wave, but without
            // this fence TBAA permits hoisting the ds_read_b128 of P above
            // the softmax stores -> stale-P race (run-to-run nondeterminism).
            asm volatile("" ::: "memory");
            floatx4 o0 = (floatx4)0.0f, o1 = (floatx4)0.0f;
            #pragma unroll
            for (int sl = 0; sl < 5; ++sl) {
                bf16x8 pf = lds_ld8(&lds[Po + (wv * 5 + sl) * 512 + lane * 8]);
                o0 = mfma16(pf, *(const bf16x8*)&lds[V2o + ((hlB * 2 + 0) * 5 + sl) * 512 + lane * 8], o0);
                o1 = mfma16(pf, *(const bf16x8*)&lds[V2o + ((hlB * 2 + 1) * 5 + sl) * 512 + lane * 8], o1);
            }
            Oacc[g][it][0] = o0; Oacc[g][it][1] = o1;
        }
    }

    // ---- phase C: O C-layout -> A-frags in XF region (x no longer needed) ----
    #pragma unroll
    for (int g = 0; g < 3; ++g) {
        int hB = 2 * g + hlB;
        #pragma unroll
        for (int it = 0; it < 3; ++it) {
            int s = s0 + 3 * it;
            #pragma unroll
            for (int ntv = 0; ntv < 2; ++ntv) {
                #pragma unroll
                for (int r = 0; r < 4; ++r) {
                    lds[XFo + (hB * 9 + s) * 512 +
                        ((q * 4 + r) + 16 * (ntv * 2 + (c >> 3))) * 8 + (c & 7)] =
                        f2bf(Oacc[g][it][ntv][r]);
                }
            }
        }
    }
    __syncthreads();

    // ---- out-proj: wave owns 2 output col-tiles ----
    {
        const int colt0 = 2 * wv;
        const unsigned short* wh0p = woh_g + (size_t)(colt0 * 6) * 512 + lane * 8;
        const unsigned short* wh1p = woh_g + (size_t)((colt0 + 1) * 6) * 512 + lane * 8;
        const unsigned short* wl0p = wol_g + (size_t)(colt0 * 6) * 512 + lane * 8;
        const unsigned short* wl1p = wol_g + (size_t)((colt0 + 1) * 6) * 512 + lane * 8;
        bf16x8 wh0[6], wh1[6];
        #pragma unroll
        for (int kt = 0; kt < 6; ++kt) {
            wh0[kt] = *(const bf16x8*)&wh0p[kt * 512];
            wh1[kt] = *(const bf16x8*)&wh1p[kt * 512];
        }
        float bo0 = b_out[colt0 * 16 + c];
        float bo1 = b_out[colt0 * 16 + 16 + c];
        #pragma unroll
        for (int i3 = 0; i3 < 3; ++i3) {
            floatx4 a2[3][2];
            #pragma unroll
            for (int ii = 0; ii < 3; ++ii) { a2[ii][0] = (floatx4)0.0f; a2[ii][1] = (floatx4)0.0f; }
            #pragma unroll
            for (int kt = 0; kt < 6; ++kt) {
                bf16x8 wlo0 = *(const bf16x8*)&wl0p[kt * 512];
                bf16x8 wlo1 = *(const bf16x8*)&wl1p[kt * 512];
                #pragma unroll
                for (int ii = 0; ii < 3; ++ii) {
                    bf16x8 af = *(const bf16x8*)&lds[XFo + (kt * 9 + i3 * 3 + ii) * 512 + lane * 8];
                    a2[ii][0] = mfma16(af, wh0[kt], a2[ii][0]);
                    a2[ii][0] = mfma16(af, wlo0, a2[ii][0]);
                    a2[ii][1] = mfma16(af, wh1[kt], a2[ii][1]);
                    a2[ii][1] = mfma16(af, wlo1, a2[ii][1]);
                }
            }
            #pragma unroll
            for (int ii = 0; ii < 3; ++ii) {
                int n0 = (i3 * 3 + ii) * 16 + q * 4;
                #pragma unroll
                for (int r = 0; r < 4; ++r) {
                    size_t ro = ((size_t)w * NT + n0 + r) * DIM;
                    out[ro + colt0 * 16 + c] = a2[ii][0][r] + bo0;
                    out[ro + colt0 * 16 + 16 + c] = a2[ii][1][r] + bo1;
                }
            }
        }
    }
}

// ===========================================================================
// Zero-ws fallback (R1 fp32 kernels, verified)
// ===========================================================================
__global__ __launch_bounds__(256, 2)
void attn_kernel(const float* __restrict__ x, const int* __restrict__ mask,
                 const int* __restrict__ rel_index, const float* __restrict__ w_qkv,
                 const float* __restrict__ b_qkv, const float* __restrict__ bias_table,
                 float* __restrict__ out)
{
    __shared__ float smem[19136];
    float* xt = smem;
    float* wt = smem + 4768;
    float* qs = smem;
    float* ks = smem + 4752;
    float* vs = smem + 9504;
    float* S  = smem + 14400;

    const int t  = threadIdx.x;
    const int w  = blockIdx.x / NH;
    const int h  = blockIdx.x % NH;
    const int tx = t & 15;
    const int ty = t >> 4;
    const float scale = 0.17677669529663687f;
    const float* xg = x + (size_t)w * NT * DIM;

    float acc[9][6];
    #pragma unroll
    for (int i = 0; i < 9; ++i)
        #pragma unroll
        for (int j = 0; j < 6; ++j) acc[i][j] = 0.f;

    for (int kt = 0; kt < 6; ++kt) {
        #pragma unroll
        for (int l = 0; l < 18; ++l) {
            int e = t + l * 256;
            int n = e >> 5, kk = e & 31;
            xt[kk * 149 + n] = xg[n * DIM + kt * 32 + kk];
        }
        #pragma unroll
        for (int l = 0; l < 12; ++l) {
            int e = t + l * 256;
            int kk = e / 96, cc = e - kk * 96;
            int col = (cc >> 5) * DIM + h * HD + (cc & 31);
            wt[kk * 96 + cc] = w_qkv[(kt * 32 + kk) * WCOLS + col];
        }
        __syncthreads();
        #pragma unroll
        for (int kk = 0; kk < 32; ++kk) {
            float a[9], b[6];
            #pragma unroll
            for (int i = 0; i < 9; ++i) a[i] = xt[kk * 149 + ty * 9 + i];
            #pragma unroll
            for (int j = 0; j < 6; ++j) b[j] = wt[kk * 96 + tx * 6 + j];
            #pragma unroll
            for (int i = 0; i < 9; ++i)
                #pragma unroll
                for (int j = 0; j < 6; ++j) acc[i][j] = fmaf(a[i], b[j], acc[i][j]);
        }
        __syncthreads();
    }

    #pragma unroll
    for (int j = 0; j < 6; ++j) {
        int cc = tx * 6 + j;
        int part = cc >> 5, jj = cc & 31;
        float bq = b_qkv[part * DIM + h * HD + jj];
        #pragma unroll
        for (int i = 0; i < 9; ++i) {
            int r = ty * 9 + i;
            float val = acc[i][j] + bq;
            if (part == 0)      qs[r * 33 + jj] = val * scale;
            else if (part == 1) ks[r * 33 + jj] = val;
            else                vs[r * 34 + jj] = val;
        }
    }
    __syncthreads();

    const int wave = t >> 6, lane = t & 63;
    for (int rt = 0; rt < 5; ++rt) {
        const int rows = (rt == 4) ? 16 : 32;
        {
            int r0 = ty * 2;
            int n0 = rt * 32 + r0; if (n0 > NT - 1) n0 = NT - 1;
            int n1 = n0 + 1;       if (n1 > NT - 1) n1 = NT - 1;
            int m0 = tx * 9;
            float s0[9], s1[9];
            #pragma unroll
            for (int j = 0; j < 9; ++j) { s0[j] = 0.f; s1[j] = 0.f; }
            #pragma unroll
            for (int kk = 0; kk < 32; ++kk) {
                float a0 = qs[n0 * 33 + kk];
                float a1 = qs[n1 * 33 + kk];
                #pragma unroll
                for (int j = 0; j < 9; ++j) {
                    float bk = ks[(m0 + j) * 33 + kk];
                    s0[j] = fmaf(a0, bk, s0[j]);
                    s1[j] = fmaf(a1, bk, s1[j]);
                }
            }
            if (r0 < rows) {
                #pragma unroll
                for (int j = 0; j < 9; ++j) S[r0 * 148 + m0 + j] = s0[j];
                #pragma unroll
                for (int j = 0; j < 9; ++j) S[(r0 + 1) * 148 + m0 + j] = s1[j];
            }
        }
        __syncthreads();

        for (int r = wave; r < rows; r += 4) {
            int n = rt * 32 + r;
            const int* mrow = mask + ((size_t)w * NT + n) * NT;
            const int* rrow = rel_index + n * NT;
            float e0 = S[r * 148 + lane] + bias_table[rrow[lane] * NH + h];
            if (mrow[lane] == 0) e0 = -1e9f;
            float e1 = S[r * 148 + 64 + lane] + bias_table[rrow[64 + lane] * NH + h];
            if (mrow[64 + lane] == 0) e1 = -1e9f;
            float e2 = -INFINITY;
            if (lane < 16) {
                e2 = S[r * 148 + 128 + lane] + bias_table[rrow[128 + lane] * NH + h];
                if (mrow[128 + lane] == 0) e2 = -1e9f;
            }
            float vmax = fmaxf(fmaxf(e0, e1), e2);
            #pragma unroll
            for (int off = 32; off > 0; off >>= 1)
                vmax = fmaxf(vmax, __shfl_xor(vmax, off, 64));
            float p0 = __expf(e0 - vmax);
            float p1 = __expf(e1 - vmax);
            float p2 = (lane < 16) ? __expf(e2 - vmax) : 0.f;
            float s = p0 + p1 + p2;
            #pragma unroll
            for (int off = 32; off > 0; off >>= 1)
                s += __shfl_xor(s, off, 64);
            float rinv = 1.f / s;
            S[r * 148 + lane] = p0 * rinv;
            S[r * 148 + 64 + lane] = p1 * rinv;
            if (lane < 16) S[r * 148 + 128 + lane] = p2 * rinv;
        }
        __syncthreads();

        {
            int r0 = ty * 2, dd0 = tx * 2;
            if (r0 < rows) {
                float o00 = 0, o01 = 0, o10 = 0, o11 = 0;
                #pragma unroll
                for (int m = 0; m < NT; ++m) {
                    float p0 = S[r0 * 148 + m];
                    float p1 = S[(r0 + 1) * 148 + m];
                    float2 vv = *(const float2*)&vs[m * 34 + dd0];
                    o00 = fmaf(p0, vv.x, o00);
                    o01 = fmaf(p0, vv.y, o01);
                    o10 = fmaf(p1, vv.x, o10);
                    o11 = fmaf(p1, vv.y, o11);
                }
                int n0 = rt * 32 + r0;
                *(float2*)&out[((size_t)(w * NT + n0)) * DIM + h * HD + dd0] = make_float2(o00, o01);
                *(float2*)&out[((size_t)(w * NT + n0 + 1)) * DIM + h * HD + dd0] = make_float2(o10, o11);
            }
        }
        __syncthreads();
    }
}

__global__ __launch_bounds__(256, 2)
void proj_kernel(float* __restrict__ io, const float* __restrict__ w_out,
                 const float* __restrict__ b_out)
{
    __shared__ float in_t[64 * 196];
    __shared__ float wt[32 * 192];
    const int t = threadIdx.x;
    const size_t row0 = (size_t)blockIdx.x * 64;

    #pragma unroll
    for (int l = 0; l < 12; ++l) {
        int e = t + l * 256;
        int r = e / 48, c4 = e - r * 48;
        float4 val = *(const float4*)&io[(row0 + r) * DIM + c4 * 4];
        *(float4*)&in_t[r * 196 + c4 * 4] = val;
    }
    const int tx = t & 15, ty = t >> 4;
    float acc[4][12];
    #pragma unroll
    for (int i = 0; i < 4; ++i)
        #pragma unroll
        for (int j = 0; j < 12; ++j) acc[i][j] = 0.f;

    for (int kt = 0; kt < 6; ++kt) {
        __syncthreads();
        #pragma unroll
        for (int l = 0; l < 6; ++l) {
            int e = t + l * 256;
            int kk = e / 48, c4 = e - kk * 48;
            *(float4*)&wt[kk * 192 + c4 * 4] =
                *(const float4*)&w_out[(kt * 32 + kk) * DIM + c4 * 4];
        }
        __syncthreads();
        #pragma unroll
        for (int kk = 0; kk < 32; ++kk) {
            float a[4];
            #pragma unroll
            for (int i = 0; i < 4; ++i) a[i] = in_t[(ty * 4 + i) * 196 + kt * 32 + kk];
            float b[12];
            #pragma unroll
            for (int j4 = 0; j4 < 3; ++j4) {
                float4 bb = *(const float4*)&wt[kk * 192 + tx * 12 + j4 * 4];
                b[j4 * 4] = bb.x; b[j4 * 4 + 1] = bb.y;
                b[j4 * 4 + 2] = bb.z; b[j4 * 4 + 3] = bb.w;
            }
            #pragma unroll
            for (int i = 0; i < 4; ++i)
                #pragma unroll
                for (int j = 0; j < 12; ++j)
                    acc[i][j] = fmaf(a[i], b[j], acc[i][j]);
        }
    }

    float bo[12];
    #pragma unroll
    for (int j4 = 0; j4 < 3; ++j4) {
        float4 bb = *(const float4*)&b_out[tx * 12 + j4 * 4];
        bo[j4 * 4] = bb.x; bo[j4 * 4 + 1] = bb.y;
        bo[j4 * 4 + 2] = bb.z; bo[j4 * 4 + 3] = bb.w;
    }
    #pragma unroll
    for (int i = 0; i < 4; ++i) {
        size_t r = row0 + ty * 4 + i;
        #pragma unroll
        for (int j4 = 0; j4 < 3; ++j4) {
            float4 o;
            o.x = acc[i][j4 * 4]     + bo[j4 * 4];
            o.y = acc[i][j4 * 4 + 1] + bo[j4 * 4 + 1];
            o.z = acc[i][j4 * 4 + 2] + bo[j4 * 4 + 2];
            o.w = acc[i][j4 * 4 + 3] + bo[j4 * 4 + 3];
            *(float4*)&io[r * DIM + tx * 12 + j4 * 4] = o;
        }
    }
}

// ===========================================================================
extern "C" void kernel_launch(void* const* d_in, const int* in_sizes, int n_in,
                              void* d_out, int out_size, void* d_ws, size_t ws_size,
                              hipStream_t stream) {
    const float* x          = (const float*)d_in[0];
    const int*   mask       = (const int*)d_in[1];
    const int*   rel_index  = (const int*)d_in[2];
    const float* w_qkv      = (const float*)d_in[3];
    const float* b_qkv      = (const float*)d_in[4];
    const float* w_out      = (const float*)d_in[5];
    const float* b_out      = (const float*)d_in[6];
    const float* bias_table = (const float*)d_in[7];
    float* out = (float*)d_out;

    // ws layout (bytes):
    //   bias_pre @0        : 497664
    //   wq_h     @497664   : 221184   (frag layout)
    //   wq_l     @718848   : 221184
    //   wo_h     @940032   :  73728   (frag layout)
    //   wo_l     @1013760  :  73728   -> total 1087488
    const size_t WS_NEED = 1087488;

    if (ws_size >= WS_NEED) {
        char* ws = (char*)d_ws;
        float*          bias_pre = (float*)ws;
        unsigned short* wq_h     = (unsigned short*)(ws + 497664);
        unsigned short* wq_l     = (unsigned short*)(ws + 718848);
        unsigned short* wo_h     = (unsigned short*)(ws + 940032);
        unsigned short* wo_l     = (unsigned short*)(ws + 1013760);

        hipLaunchKernelGGL(prep_bias, dim3(486), dim3(256), 0, stream,
                           rel_index, bias_table, bias_pre);
        hipLaunchKernelGGL(prep_wq_frag, dim3(432), dim3(256), 0, stream,
                           w_qkv, wq_h, wq_l);
        hipLaunchKernelGGL(prep_wo_frag, dim3(144), dim3(256), 0, stream,
                           w_out, wo_h, wo_l);
        hipLaunchKernelGGL(fused, dim3(NW), dim3(384), 0, stream,
                           x, mask, bias_pre, wq_h, wq_l, b_qkv,
                           wo_h, wo_l, b_out, out);
    } else {
        hipLaunchKernelGGL(attn_kernel, dim3(NW * NH), dim3(256), 0, stream,
                           x, mask, rel_index, w_qkv, b_qkv, bias_table, out);
        hipLaunchKernelGGL(proj_kernel, dim3(NW * NT / 64), dim3(256), 0, stream,
                           out, w_out, b_out);
    }
}

// Round 3
// 529.321 us; speedup vs baseline: 1.0765x; 1.0765x over previous
//
#include <hip/hip_runtime.h>
#include <math.h>

#define NW 960
#define NT 144
#define DIM 192
#define NH 6
#define HD 32
#define WCOLS 576

typedef __bf16 bf16x8 __attribute__((ext_vector_type(8)));
typedef float floatx4 __attribute__((ext_vector_type(4)));

__device__ __forceinline__ unsigned short f2bf(float x) {
    union { float f; unsigned u; } v; v.f = x;
    unsigned r = v.u + 0x7fffu + ((v.u >> 16) & 1u);
    return (unsigned short)(r >> 16);
}
__device__ __forceinline__ float bf2f(unsigned short b) {
    union { unsigned u; float f; } v; v.u = ((unsigned)b) << 16;
    return v.f;
}
__device__ __forceinline__ floatx4 mfma16(bf16x8 a, bf16x8 b, floatx4 c) {
    return __builtin_amdgcn_mfma_f32_16x16x32_bf16(a, b, c, 0, 0, 0);
}
// Aliasing-safe LDS vector load: used where a bf16x8 read must not be
// reordered above preceding unsigned-short stores to the same region
// (TBAA would otherwise allow the hoist - the P tile is the only LDS
// RAW seam not protected by __syncthreads()).
__device__ __forceinline__ bf16x8 lds_ld8(const unsigned short* p) {
    bf16x8 v;
    __builtin_memcpy(&v, p, 16);
    return v;
}

// ===========================================================================
// Prep kernels (tiny; weights + bias only)
// ===========================================================================
__global__ void prep_bias(const int* __restrict__ rel_index,
                          const float* __restrict__ bias_table,
                          float* __restrict__ bias_pre) {
    int i = blockIdx.x * 256 + threadIdx.x;           // [6][144][144]
    if (i < NH * NT * NT) {
        int h = i / (NT * NT);
        int rem = i - h * (NT * NT);
        bias_pre[i] = bias_table[rel_index[rem] * NH + h];
    }
}

// wq frag: [h][j(6)][kt(6)][lane(64)][pos(8)]
__global__ void prep_wq_frag(const float* __restrict__ w_qkv,
                             unsigned short* __restrict__ wh,
                             unsigned short* __restrict__ wl) {
    int i = blockIdx.x * 256 + threadIdx.x;           // 6*6*6*512 = 110592
    if (i < NH * 6 * 6 * 512) {
        int h = i / 18432; int r = i - h * 18432;
        int j = r / 3072;  r -= j * 3072;
        int kt = r / 512;  r -= kt * 512;
        int lane = r >> 3, pos = r & 7;
        int col96 = j * 16 + (lane & 15);
        int k = kt * 32 + (lane >> 4) * 8 + pos;
        float v = w_qkv[k * WCOLS + (col96 >> 5) * DIM + h * HD + (col96 & 31)];
        unsigned short hi = f2bf(v);
        wh[i] = hi;
        wl[i] = f2bf(v - bf2f(hi));
    }
}

// wout frag: [nt(12)][kt(6)][lane(64)][pos(8)]
__global__ void prep_wo_frag(const float* __restrict__ w_out,
                             unsigned short* __restrict__ wh,
                             unsigned short* __restrict__ wl) {
    int i = blockIdx.x * 256 + threadIdx.x;           // 12*6*512 = 36864
    if (i < 12 * 6 * 512) {
        int nt = i / 3072; int r = i - nt * 3072;
        int kt = r / 512;  r -= kt * 512;
        int lane = r >> 3, pos = r & 7;
        int ocol = nt * 16 + (lane & 15);
        int k = kt * 32 + (lane >> 4) * 8 + pos;
        float v = w_out[k * DIM + ocol];
        unsigned short hi = f2bf(v);
        wh[i] = hi;
        wl[i] = f2bf(v - bf2f(hi));
    }
}

// ===========================================================================
// Fused: QKV + attention (6 heads) + out-proj, one block per window.
// 384 threads (6 waves). LDS (shorts, total 73120 = 146240 B):
//   XF [kt6][tile9][512] @0      (27648)  -- x bf16 A-frags; reused as O-frags
//   Q2 [hl2][tile9][512] @27648  (9216)
//   K2 [hl2][tile9][512] @36864  (9216)
//   V2t[4][slab5][512]   @46080  (10240)  -- (hl*2+ntv) groups
//   P  [wv6][slab5][512] @56320  (15360)
//   MB [144][5] u32      @71680  (1440 sh)
// NOTE __launch_bounds__(384,1): LDS already caps us at 1 block/CU, so the
// old (384,2) only capped VGPR at 128 for nothing. 1 block of 6 waves needs
// at most 2 waves/SIMD even at 256 VGPR -> free register headroom.
// ===========================================================================
__global__ __launch_bounds__(384, 1)
void fused(const float* __restrict__ x, const int* __restrict__ mask,
           const float* __restrict__ bias_pre,
           const unsigned short* __restrict__ wqh, const unsigned short* __restrict__ wql,
           const float* __restrict__ b_qkv,
           const unsigned short* __restrict__ woh_g, const unsigned short* __restrict__ wol_g,
           const float* __restrict__ b_out, float* __restrict__ out)
{
    __shared__ __align__(16) unsigned short lds[73120];
    const int XFo = 0, Q2o = 27648, K2o = 36864, V2o = 46080, Po = 56320, MBo = 71680;

    const int t = threadIdx.x;
    const int w = blockIdx.x;
    const int lane = t & 63, wv = t >> 6;
    const int c = lane & 15, q = lane >> 4;
    const float scale = 0.17677669529663687f;
    const float* xg = x + (size_t)w * NT * DIM;

    // ---- stage x -> XF bf16 A-frags (13824 dwords) ----
    {
        unsigned* XFd = (unsigned*)&lds[XFo];
        #pragma unroll
        for (int l = 0; l < 36; ++l) {
            int d = t + l * 384;
            int kt = d / 2304; int r2 = d - kt * 2304;
            int tile = r2 >> 8; int r3 = r2 & 255;
            int ln = r3 >> 2, pp = r3 & 3;
            int n = tile * 16 + (ln & 15);
            int k = kt * 32 + (ln >> 4) * 8 + pp * 2;
            float2 xv = *(const float2*)&xg[n * DIM + k];
            XFd[d] = (unsigned)f2bf(xv.x) | ((unsigned)f2bf(xv.y) << 16);
        }
    }
    // ---- zero pads: V2t tokens 144..159, P k 144..159 ----
    for (int e = t; e < 2560; e += 384) {
        if (e < 1024) {
            int gi = e >> 8, l2 = 32 + ((e >> 3) & 31), pos = e & 7;
            lds[V2o + (gi * 5 + 4) * 512 + l2 * 8 + pos] = 0;
        } else {
            int e2 = e - 1024;
            int wvi = e2 >> 8, l2 = 32 + ((e2 >> 3) & 31), pos = e2 & 7;
            lds[Po + (wvi * 5 + 4) * 512 + l2 * 8 + pos] = 0;
        }
    }
    // ---- mask -> bit-packed MB via ballot (coalesced, read once per window) ----
    {
        unsigned* mb = (unsigned*)&lds[MBo];
        #pragma unroll 4
        for (int rr = 0; rr < 24; ++rr) {
            int n = wv * 24 + rr;
            const int* mrow = mask + ((size_t)w * NT + n) * NT;
            unsigned long long b0 = __ballot(mrow[lane] != 0);
            unsigned long long b1 = __ballot(mrow[64 + lane] != 0);
            int mv = (lane < 16) ? mrow[128 + lane] : 0;
            unsigned long long b2 = __ballot(mv != 0);
            if (lane == 0) {
                mb[n * 5 + 0] = (unsigned)b0;
                mb[n * 5 + 1] = (unsigned)(b0 >> 32);
                mb[n * 5 + 2] = (unsigned)b1;
                mb[n * 5 + 3] = (unsigned)(b1 >> 32);
                mb[n * 5 + 4] = (unsigned)b2;
            }
        }
    }

    const int part = wv % 3;        // phase-A role: 0=Q,1=K,2=V columns
    const int hlA  = wv / 3;        // phase-A head-in-group
    const int j0   = part * 2;
    const int hlB  = wv & 1;        // phase-B head-in-group
    const int s0   = wv >> 1;       // phase-B base strip

    floatx4 Oacc[3][3][2];

    #pragma unroll
    for (int g = 0; g < 3; ++g) {
        __syncthreads();            // XF/MB ready (g=0) / prev group's B reads done
        const int hg = 2 * g + hlA;

        // hoisted B-frags (hi AND lo) for this wave's 2 column-tiles
        const unsigned short* bh0p = wqh + (size_t)((hg * 6 + j0) * 6) * 512 + lane * 8;
        const unsigned short* bh1p = wqh + (size_t)((hg * 6 + j0 + 1) * 6) * 512 + lane * 8;
        const unsigned short* bl0p = wql + (size_t)((hg * 6 + j0) * 6) * 512 + lane * 8;
        const unsigned short* bl1p = wql + (size_t)((hg * 6 + j0 + 1) * 6) * 512 + lane * 8;
        bf16x8 bh0[6], bh1[6], bl0a[6], bl1a[6];
        #pragma unroll
        for (int kt = 0; kt < 6; ++kt) {
            bh0[kt]  = *(const bf16x8*)&bh0p[kt * 512];
            bh1[kt]  = *(const bf16x8*)&bh1p[kt * 512];
            bl0a[kt] = *(const bf16x8*)&bl0p[kt * 512];
            bl1a[kt] = *(const bf16x8*)&bl1p[kt * 512];
        }
        float bq0 = b_qkv[part * DIM + hg * HD + c];
        float bq1 = b_qkv[part * DIM + hg * HD + 16 + c];

        // ---- QKV gemm for this group's 2 column-tiles of this wave ----
        #pragma unroll
        for (int i3 = 0; i3 < 3; ++i3) {
            floatx4 a[3][2];
            #pragma unroll
            for (int ii = 0; ii < 3; ++ii) { a[ii][0] = (floatx4)0.0f; a[ii][1] = (floatx4)0.0f; }
            __builtin_amdgcn_s_setprio(1);
            #pragma unroll
            for (int kt = 0; kt < 6; ++kt) {
                #pragma unroll
                for (int ii = 0; ii < 3; ++ii) {
                    bf16x8 ah = *(const bf16x8*)&lds[XFo + (kt * 9 + i3 * 3 + ii) * 512 + lane * 8];
                    a[ii][0] = mfma16(ah, bh0[kt], a[ii][0]);
                    a[ii][0] = mfma16(ah, bl0a[kt], a[ii][0]);
                    a[ii][1] = mfma16(ah, bh1[kt], a[ii][1]);
                    a[ii][1] = mfma16(ah, bl1a[kt], a[ii][1]);
                }
            }
            __builtin_amdgcn_s_setprio(0);
            // scatter C-layout -> frag layouts (verified formulas from R3)
            #pragma unroll
            for (int ii = 0; ii < 3; ++ii) {
                int i = i3 * 3 + ii;
                #pragma unroll
                for (int r = 0; r < 4; ++r) {
                    float v0 = a[ii][0][r] + bq0;
                    float v1 = a[ii][1][r] + bq1;
                    if (part == 0) {
                        lds[Q2o + (hlA * 9 + i) * 512 + ((q * 4 + r) + 16 * (c >> 3)) * 8 + (c & 7)] = f2bf(v0 * scale);
                        lds[Q2o + (hlA * 9 + i) * 512 + ((q * 4 + r) + 16 * (2 + (c >> 3))) * 8 + (c & 7)] = f2bf(v1 * scale);
                    } else if (part == 1) {
                        lds[K2o + (hlA * 9 + i) * 512 + ((q * 4 + r) + 16 * (c >> 3)) * 8 + (c & 7)] = f2bf(v0);
                        lds[K2o + (hlA * 9 + i) * 512 + ((q * 4 + r) + 16 * (2 + (c >> 3))) * 8 + (c & 7)] = f2bf(v1);
                    } else {
                        int n = i * 16 + q * 4 + r;
                        lds[V2o + ((hlA * 2 + 0) * 5 + (n >> 5)) * 512 + (c + 16 * ((n >> 3) & 3)) * 8 + (n & 7)] = f2bf(v0);
                        lds[V2o + ((hlA * 2 + 1) * 5 + (n >> 5)) * 512 + (c + 16 * ((n >> 3) & 3)) * 8 + (n & 7)] = f2bf(v1);
                    }
                }
            }
        }
        __syncthreads();

        // ---- attention: 3 units/wave (even split), barrier-free ----
        const int hB = 2 * g + hlB;
        #pragma unroll
        for (int it = 0; it < 3; ++it) {
            int s = s0 + 3 * it;
            // Issue all 36 bias loads up-front (4 rows x 9 chunks, independent
            // of the QK MFMAs below -> L2 latency hides under them).
            float bb[4][9];
            const float* bbase = bias_pre + hB * (NT * NT) + (s * 16 + q * 4) * NT + c;
            #pragma unroll
            for (int r = 0; r < 4; ++r)
                #pragma unroll
                for (int nt = 0; nt < 9; ++nt)
                    bb[r][nt] = bbase[r * NT + nt * 16];
            bf16x8 qf = *(const bf16x8*)&lds[Q2o + (hlB * 9 + s) * 512 + lane * 8];
            floatx4 sacc[9];
            __builtin_amdgcn_s_setprio(1);
            #pragma unroll
            for (int nt = 0; nt < 9; ++nt) {
                bf16x8 kf = *(const bf16x8*)&lds[K2o + (hlB * 9 + nt) * 512 + lane * 8];
                sacc[nt] = mfma16(qf, kf, (floatx4)0.0f);
            }
            __builtin_amdgcn_s_setprio(0);
            const unsigned* mb = (const unsigned*)&lds[MBo];
            unsigned mwv[4][5];
            #pragma unroll
            for (int r = 0; r < 4; ++r) {
                int n = s * 16 + q * 4 + r;
                #pragma unroll
                for (int k5 = 0; k5 < 5; ++k5) mwv[r][k5] = mb[n * 5 + k5];
            }
            // Batched softmax: the 4 row-chains (r=0..3) are independent;
            // interleaving them gives 4-way ILP on the shfl reduce chains
            // instead of 4 serialized chains. Per-row operand order is
            // unchanged -> bit-identical results.
            float e[4][9], mx[4];
            #pragma unroll
            for (int r = 0; r < 4; ++r) mx[r] = -1e30f;
            #pragma unroll
            for (int r = 0; r < 4; ++r)
                #pragma unroll
                for (int nt = 0; nt < 9; ++nt) {
                    float val = sacc[nt][r] + bb[r][nt];
                    unsigned bit = (mwv[r][nt >> 1] >> (((nt & 1) << 4) + c)) & 1u;
                    val = bit ? val : -1e9f;
                    e[r][nt] = val; mx[r] = fmaxf(mx[r], val);
                }
            #pragma unroll
            for (int o = 8; o; o >>= 1)
                #pragma unroll
                for (int r = 0; r < 4; ++r) mx[r] = fmaxf(mx[r], __shfl_xor(mx[r], o, 64));
            float sum[4] = {0.f, 0.f, 0.f, 0.f};
            #pragma unroll
            for (int r = 0; r < 4; ++r)
                #pragma unroll
                for (int nt = 0; nt < 9; ++nt) { e[r][nt] = __expf(e[r][nt] - mx[r]); sum[r] += e[r][nt]; }
            #pragma unroll
            for (int o = 8; o; o >>= 1)
                #pragma unroll
                for (int r = 0; r < 4; ++r) sum[r] += __shfl_xor(sum[r], o, 64);
            #pragma unroll
            for (int r = 0; r < 4; ++r) {
                float rinv = 1.0f / sum[r];
                #pragma unroll
                for (int nt = 0; nt < 9; ++nt) {
                    int col = nt * 16 + c;
                    lds[Po + (wv * 5 + (col >> 5)) * 512 +
                        ((q * 4 + r) + 16 * ((col >> 3) & 3)) * 8 + (col & 7)] = f2bf(e[r][nt] * rinv);
                }
            }
            // Compiler memory fence: the P-tile stores above and the P-frag
            // loads below alias through different types (unsigned short vs
            // __bf16 vector); hardware DS is in-order per wave, but without
            // this fence TBAA permits hoisting the ds_read_b128 of P above
            // the softmax stores -> stale-P race (run-to-run nondeterminism).
            asm volatile("" ::: "memory");
            floatx4 o0 = (floatx4)0.0f, o1 = (floatx4)0.0f;
            __builtin_amdgcn_s_setprio(1);
            #pragma unroll
            for (int sl = 0; sl < 5; ++sl) {
                bf16x8 pf = lds_ld8(&lds[Po + (wv * 5 + sl) * 512 + lane * 8]);
                o0 = mfma16(pf, *(const bf16x8*)&lds[V2o + ((hlB * 2 + 0) * 5 + sl) * 512 + lane * 8], o0);
                o1 = mfma16(pf, *(const bf16x8*)&lds[V2o + ((hlB * 2 + 1) * 5 + sl) * 512 + lane * 8], o1);
            }
            __builtin_amdgcn_s_setprio(0);
            Oacc[g][it][0] = o0; Oacc[g][it][1] = o1;
        }
    }

    // ---- phase C: O C-layout -> A-frags in XF region (x no longer needed) ----
    #pragma unroll
    for (int g = 0; g < 3; ++g) {
        int hB = 2 * g + hlB;
        #pragma unroll
        for (int it = 0; it < 3; ++it) {
            int s = s0 + 3 * it;
            #pragma unroll
            for (int ntv = 0; ntv < 2; ++ntv) {
                #pragma unroll
                for (int r = 0; r < 4; ++r) {
                    lds[XFo + (hB * 9 + s) * 512 +
                        ((q * 4 + r) + 16 * (ntv * 2 + (c >> 3))) * 8 + (c & 7)] =
                        f2bf(Oacc[g][it][ntv][r]);
                }
            }
        }
    }
    __syncthreads();

    // ---- out-proj: wave owns 2 output col-tiles ----
    {
        const int colt0 = 2 * wv;
        const unsigned short* wh0p = woh_g + (size_t)(colt0 * 6) * 512 + lane * 8;
        const unsigned short* wh1p = woh_g + (size_t)((colt0 + 1) * 6) * 512 + lane * 8;
        const unsigned short* wl0p = wol_g + (size_t)(colt0 * 6) * 512 + lane * 8;
        const unsigned short* wl1p = wol_g + (size_t)((colt0 + 1) * 6) * 512 + lane * 8;
        bf16x8 wh0[6], wh1[6], wlo0[6], wlo1[6];
        #pragma unroll
        for (int kt = 0; kt < 6; ++kt) {
            wh0[kt]  = *(const bf16x8*)&wh0p[kt * 512];
            wh1[kt]  = *(const bf16x8*)&wh1p[kt * 512];
            wlo0[kt] = *(const bf16x8*)&wl0p[kt * 512];
            wlo1[kt] = *(const bf16x8*)&wl1p[kt * 512];
        }
        float bo0 = b_out[colt0 * 16 + c];
        float bo1 = b_out[colt0 * 16 + 16 + c];
        #pragma unroll
        for (int i3 = 0; i3 < 3; ++i3) {
            floatx4 a2[3][2];
            #pragma unroll
            for (int ii = 0; ii < 3; ++ii) { a2[ii][0] = (floatx4)0.0f; a2[ii][1] = (floatx4)0.0f; }
            __builtin_amdgcn_s_setprio(1);
            #pragma unroll
            for (int kt = 0; kt < 6; ++kt) {
                #pragma unroll
                for (int ii = 0; ii < 3; ++ii) {
                    bf16x8 af = *(const bf16x8*)&lds[XFo + (kt * 9 + i3 * 3 + ii) * 512 + lane * 8];
                    a2[ii][0] = mfma16(af, wh0[kt], a2[ii][0]);
                    a2[ii][0] = mfma16(af, wlo0[kt], a2[ii][0]);
                    a2[ii][1] = mfma16(af, wh1[kt], a2[ii][1]);
                    a2[ii][1] = mfma16(af, wlo1[kt], a2[ii][1]);
                }
            }
            __builtin_amdgcn_s_setprio(0);
            #pragma unroll
            for (int ii = 0; ii < 3; ++ii) {
                int n0 = (i3 * 3 + ii) * 16 + q * 4;
                #pragma unroll
                for (int r = 0; r < 4; ++r) {
                    size_t ro = ((size_t)w * NT + n0 + r) * DIM;
                    out[ro + colt0 * 16 + c] = a2[ii][0][r] + bo0;
                    out[ro + colt0 * 16 + 16 + c] = a2[ii][1][r] + bo1;
                }
            }
        }
    }
}

// ===========================================================================
// Zero-ws fallback (R1 fp32 kernels, verified)
// ===========================================================================
__global__ __launch_bounds__(256, 2)
void attn_kernel(const float* __restrict__ x, const int* __restrict__ mask,
                 const int* __restrict__ rel_index, const float* __restrict__ w_qkv,
                 const float* __restrict__ b_qkv, const float* __restrict__ bias_table,
                 float* __restrict__ out)
{
    __shared__ float smem[19136];
    float* xt = smem;
    float* wt = smem + 4768;
    float* qs = smem;
    float* ks = smem + 4752;
    float* vs = smem + 9504;
    float* S  = smem + 14400;

    const int t  = threadIdx.x;
    const int w  = blockIdx.x / NH;
    const int h  = blockIdx.x % NH;
    const int tx = t & 15;
    const int ty = t >> 4;
    const float scale = 0.17677669529663687f;
    const float* xg = x + (size_t)w * NT * DIM;

    float acc[9][6];
    #pragma unroll
    for (int i = 0; i < 9; ++i)
        #pragma unroll
        for (int j = 0; j < 6; ++j) acc[i][j] = 0.f;

    for (int kt = 0; kt < 6; ++kt) {
        #pragma unroll
        for (int l = 0; l < 18; ++l) {
            int e = t + l * 256;
            int n = e >> 5, kk = e & 31;
            xt[kk * 149 + n] = xg[n * DIM + kt * 32 + kk];
        }
        #pragma unroll
        for (int l = 0; l < 12; ++l) {
            int e = t + l * 256;
            int kk = e / 96, cc = e - kk * 96;
            int col = (cc >> 5) * DIM + h * HD + (cc & 31);
            wt[kk * 96 + cc] = w_qkv[(kt * 32 + kk) * WCOLS + col];
        }
        __syncthreads();
        #pragma unroll
        for (int kk = 0; kk < 32; ++kk) {
            float a[9], b[6];
            #pragma unroll
            for (int i = 0; i < 9; ++i) a[i] = xt[kk * 149 + ty * 9 + i];
            #pragma unroll
            for (int j = 0; j < 6; ++j) b[j] = wt[kk * 96 + tx * 6 + j];
            #pragma unroll
            for (int i = 0; i < 9; ++i)
                #pragma unroll
                for (int j = 0; j < 6; ++j) acc[i][j] = fmaf(a[i], b[j], acc[i][j]);
        }
        __syncthreads();
    }

    #pragma unroll
    for (int j = 0; j < 6; ++j) {
        int cc = tx * 6 + j;
        int part = cc >> 5, jj = cc & 31;
        float bq = b_qkv[part * DIM + h * HD + jj];
        #pragma unroll
        for (int i = 0; i < 9; ++i) {
            int r = ty * 9 + i;
            float val = acc[i][j] + bq;
            if (part == 0)      qs[r * 33 + jj] = val * scale;
            else if (part == 1) ks[r * 33 + jj] = val;
            else                vs[r * 34 + jj] = val;
        }
    }
    __syncthreads();

    const int wave = t >> 6, lane = t & 63;
    for (int rt = 0; rt < 5; ++rt) {
        const int rows = (rt == 4) ? 16 : 32;
        {
            int r0 = ty * 2;
            int n0 = rt * 32 + r0; if (n0 > NT - 1) n0 = NT - 1;
            int n1 = n0 + 1;       if (n1 > NT - 1) n1 = NT - 1;
            int m0 = tx * 9;
            float s0[9], s1[9];
            #pragma unroll
            for (int j = 0; j < 9; ++j) { s0[j] = 0.f; s1[j] = 0.f; }
            #pragma unroll
            for (int kk = 0; kk < 32; ++kk) {
                float a0 = qs[n0 * 33 + kk];
                float a1 = qs[n1 * 33 + kk];
                #pragma unroll
                for (int j = 0; j < 9; ++j) {
                    float bk = ks[(m0 + j) * 33 + kk];
                    s0[j] = fmaf(a0, bk, s0[j]);
                    s1[j] = fmaf(a1, bk, s1[j]);
                }
            }
            if (r0 < rows) {
                #pragma unroll
                for (int j = 0; j < 9; ++j) S[r0 * 148 + m0 + j] = s0[j];
                #pragma unroll
                for (int j = 0; j < 9; ++j) S[(r0 + 1) * 148 + m0 + j] = s1[j];
            }
        }
        __syncthreads();

        for (int r = wave; r < rows; r += 4) {
            int n = rt * 32 + r;
            const int* mrow = mask + ((size_t)w * NT + n) * NT;
            const int* rrow = rel_index + n * NT;
            float e0 = S[r * 148 + lane] + bias_table[rrow[lane] * NH + h];
            if (mrow[lane] == 0) e0 = -1e9f;
            float e1 = S[r * 148 + 64 + lane] + bias_table[rrow[64 + lane] * NH + h];
            if (mrow[64 + lane] == 0) e1 = -1e9f;
            float e2 = -INFINITY;
            if (lane < 16) {
                e2 = S[r * 148 + 128 + lane] + bias_table[rrow[128 + lane] * NH + h];
                if (mrow[128 + lane] == 0) e2 = -1e9f;
            }
            float vmax = fmaxf(fmaxf(e0, e1), e2);
            #pragma unroll
            for (int off = 32; off > 0; off >>= 1)
                vmax = fmaxf(vmax, __shfl_xor(vmax, off, 64));
            float p0 = __expf(e0 - vmax);
            float p1 = __expf(e1 - vmax);
            float p2 = (lane < 16) ? __expf(e2 - vmax) : 0.f;
            float s = p0 + p1 + p2;
            #pragma unroll
            for (int off = 32; off > 0; off >>= 1)
                s += __shfl_xor(s, off, 64);
            float rinv = 1.f / s;
            S[r * 148 + lane] = p0 * rinv;
            S[r * 148 + 64 + lane] = p1 * rinv;
            if (lane < 16) S[r * 148 + 128 + lane] = p2 * rinv;
        }
        __syncthreads();

        {
            int r0 = ty * 2, dd0 = tx * 2;
            if (r0 < rows) {
                float o00 = 0, o01 = 0, o10 = 0, o11 = 0;
                #pragma unroll
                for (int m = 0; m < NT; ++m) {
                    float p0 = S[r0 * 148 + m];
                    float p1 = S[(r0 + 1) * 148 + m];
                    float2 vv = *(const float2*)&vs[m * 34 + dd0];
                    o00 = fmaf(p0, vv.x, o00);
                    o01 = fmaf(p0, vv.y, o01);
                    o10 = fmaf(p1, vv.x, o10);
                    o11 = fmaf(p1, vv.y, o11);
                }
                int n0 = rt * 32 + r0;
                *(float2*)&out[((size_t)(w * NT + n0)) * DIM + h * HD + dd0] = make_float2(o00, o01);
                *(float2*)&out[((size_t)(w * NT + n0 + 1)) * DIM + h * HD + dd0] = make_float2(o10, o11);
            }
        }
        __syncthreads();
    }
}

__global__ __launch_bounds__(256, 2)
void proj_kernel(float* __restrict__ io, const float* __restrict__ w_out,
                 const float* __restrict__ b_out)
{
    __shared__ float in_t[64 * 196];
    __shared__ float wt[32 * 192];
    const int t = threadIdx.x;
    const size_t row0 = (size_t)blockIdx.x * 64;

    #pragma unroll
    for (int l = 0; l < 12; ++l) {
        int e = t + l * 256;
        int r = e / 48, c4 = e - r * 48;
        float4 val = *(const float4*)&io[(row0 + r) * DIM + c4 * 4];
        *(float4*)&in_t[r * 196 + c4 * 4] = val;
    }
    const int tx = t & 15, ty = t >> 4;
    float acc[4][12];
    #pragma unroll
    for (int i = 0; i < 4; ++i)
        #pragma unroll
        for (int j = 0; j < 12; ++j) acc[i][j] = 0.f;

    for (int kt = 0; kt < 6; ++kt) {
        __syncthreads();
        #pragma unroll
        for (int l = 0; l < 6; ++l) {
            int e = t + l * 256;
            int kk = e / 48, c4 = e - kk * 48;
            *(float4*)&wt[kk * 192 + c4 * 4] =
                *(const float4*)&w_out[(kt * 32 + kk) * DIM + c4 * 4];
        }
        __syncthreads();
        #pragma unroll
        for (int kk = 0; kk < 32; ++kk) {
            float a[4];
            #pragma unroll
            for (int i = 0; i < 4; ++i) a[i] = in_t[(ty * 4 + i) * 196 + kt * 32 + kk];
            float b[12];
            #pragma unroll
            for (int j4 = 0; j4 < 3; ++j4) {
                float4 bb = *(const float4*)&wt[kk * 192 + tx * 12 + j4 * 4];
                b[j4 * 4] = bb.x; b[j4 * 4 + 1] = bb.y;
                b[j4 * 4 + 2] = bb.z; b[j4 * 4 + 3] = bb.w;
            }
            #pragma unroll
            for (int i = 0; i < 4; ++i)
                #pragma unroll
                for (int j = 0; j < 12; ++j)
                    acc[i][j] = fmaf(a[i], b[j], acc[i][j]);
        }
    }

    float bo[12];
    #pragma unroll
    for (int j4 = 0; j4 < 3; ++j4) {
        float4 bb = *(const float4*)&b_out[tx * 12 + j4 * 4];
        bo[j4 * 4] = bb.x; bo[j4 * 4 + 1] = bb.y;
        bo[j4 * 4 + 2] = bb.z; bo[j4 * 4 + 3] = bb.w;
    }
    #pragma unroll
    for (int i = 0; i < 4; ++i) {
        size_t r = row0 + ty * 4 + i;
        #pragma unroll
        for (int j4 = 0; j4 < 3; ++j4) {
            float4 o;
            o.x = acc[i][j4 * 4]     + bo[j4 * 4];
            o.y = acc[i][j4 * 4 + 1] + bo[j4 * 4 + 1];
            o.z = acc[i][j4 * 4 + 2] + bo[j4 * 4 + 2];
            o.w = acc[i][j4 * 4 + 3] + bo[j4 * 4 + 3];
            *(float4*)&io[r * DIM + tx * 12 + j4 * 4] = o;
        }
    }
}

// ===========================================================================
extern "C" void kernel_launch(void* const* d_in, const int* in_sizes, int n_in,
                              void* d_out, int out_size, void* d_ws, size_t ws_size,
                              hipStream_t stream) {
    const float* x          = (const float*)d_in[0];
    const int*   mask       = (const int*)d_in[1];
    const int*   rel_index  = (const int*)d_in[2];
    const float* w_qkv      = (const float*)d_in[3];
    const float* b_qkv      = (const float*)d_in[4];
    const float* w_out      = (const float*)d_in[5];
    const float* b_out      = (const float*)d_in[6];
    const float* bias_table = (const float*)d_in[7];
    float* out = (float*)d_out;

    // ws layout (bytes):
    //   bias_pre @0        : 497664
    //   wq_h     @497664   : 221184   (frag layout)
    //   wq_l     @718848   : 221184
    //   wo_h     @940032   :  73728   (frag layout)
    //   wo_l     @1013760  :  73728   -> total 1087488
    const size_t WS_NEED = 1087488;

    if (ws_size >= WS_NEED) {
        char* ws = (char*)d_ws;
        float*          bias_pre = (float*)ws;
        unsigned short* wq_h     = (unsigned short*)(ws + 497664);
        unsigned short* wq_l     = (unsigned short*)(ws + 718848);
        unsigned short* wo_h     = (unsigned short*)(ws + 940032);
        unsigned short* wo_l     = (unsigned short*)(ws + 1013760);

        hipLaunchKernelGGL(prep_bias, dim3(486), dim3(256), 0, stream,
                           rel_index, bias_table, bias_pre);
        hipLaunchKernelGGL(prep_wq_frag, dim3(432), dim3(256), 0, stream,
                           w_qkv, wq_h, wq_l);
        hipLaunchKernelGGL(prep_wo_frag, dim3(144), dim3(256), 0, stream,
                           w_out, wo_h, wo_l);
        hipLaunchKernelGGL(fused, dim3(NW), dim3(384), 0, stream,
                           x, mask, bias_pre, wq_h, wq_l, b_qkv,
                           wo_h, wo_l, b_out, out);
    } else {
        hipLaunchKernelGGL(attn_kernel, dim3(NW * NH), dim3(256), 0, stream,
                           x, mask, rel_index, w_qkv, b_qkv, bias_table, out);
        hipLaunchKernelGGL(proj_kernel, dim3(NW * NT / 64), dim3(256), 0, stream,
                           out, w_out, b_out);
    }
}

// Round 4
// 496.375 us; speedup vs baseline: 1.1479x; 1.0664x over previous
//
#include <hip/hip_runtime.h>
#include <math.h>

#define NW 960
#define NT 144
#define DIM 192
#define NH 6
#define HD 32
#define WCOLS 576

typedef __bf16 bf16x8 __attribute__((ext_vector_type(8)));
typedef float floatx4 __attribute__((ext_vector_type(4)));

__device__ __forceinline__ unsigned short f2bf(float x) {
    union { float f; unsigned u; } v; v.f = x;
    unsigned r = v.u + 0x7fffu + ((v.u >> 16) & 1u);
    return (unsigned short)(r >> 16);
}
__device__ __forceinline__ float bf2f(unsigned short b) {
    union { unsigned u; float f; } v; v.u = ((unsigned)b) << 16;
    return v.f;
}
__device__ __forceinline__ floatx4 mfma16(bf16x8 a, bf16x8 b, floatx4 c) {
    return __builtin_amdgcn_mfma_f32_16x16x32_bf16(a, b, c, 0, 0, 0);
}
// Aliasing-safe LDS vector load: used where a bf16x8 read must not be
// reordered above preceding unsigned-short stores to the same region
// (TBAA would otherwise allow the hoist - the P tile is the only LDS
// RAW seam not protected by __syncthreads()).
__device__ __forceinline__ bf16x8 lds_ld8(const unsigned short* p) {
    bf16x8 v;
    __builtin_memcpy(&v, p, 16);
    return v;
}

// ===========================================================================
// Prep kernels (tiny; weights + bias only)
// ===========================================================================
__global__ void prep_bias(const int* __restrict__ rel_index,
                          const float* __restrict__ bias_table,
                          float* __restrict__ bias_pre) {
    int i = blockIdx.x * 256 + threadIdx.x;           // [6][144][144]
    if (i < NH * NT * NT) {
        int h = i / (NT * NT);
        int rem = i - h * (NT * NT);
        bias_pre[i] = bias_table[rel_index[rem] * NH + h];
    }
}

// wq frag: [h][j(6)][kt(6)][lane(64)][pos(8)]
__global__ void prep_wq_frag(const float* __restrict__ w_qkv,
                             unsigned short* __restrict__ wh,
                             unsigned short* __restrict__ wl) {
    int i = blockIdx.x * 256 + threadIdx.x;           // 6*6*6*512 = 110592
    if (i < NH * 6 * 6 * 512) {
        int h = i / 18432; int r = i - h * 18432;
        int j = r / 3072;  r -= j * 3072;
        int kt = r / 512;  r -= kt * 512;
        int lane = r >> 3, pos = r & 7;
        int col96 = j * 16 + (lane & 15);
        int k = kt * 32 + (lane >> 4) * 8 + pos;
        float v = w_qkv[k * WCOLS + (col96 >> 5) * DIM + h * HD + (col96 & 31)];
        unsigned short hi = f2bf(v);
        wh[i] = hi;
        wl[i] = f2bf(v - bf2f(hi));
    }
}

// wout frag: [nt(12)][kt(6)][lane(64)][pos(8)]
__global__ void prep_wo_frag(const float* __restrict__ w_out,
                             unsigned short* __restrict__ wh,
                             unsigned short* __restrict__ wl) {
    int i = blockIdx.x * 256 + threadIdx.x;           // 12*6*512 = 36864
    if (i < 12 * 6 * 512) {
        int nt = i / 3072; int r = i - nt * 3072;
        int kt = r / 512;  r -= kt * 512;
        int lane = r >> 3, pos = r & 7;
        int ocol = nt * 16 + (lane & 15);
        int k = kt * 32 + (lane >> 4) * 8 + pos;
        float v = w_out[k * DIM + ocol];
        unsigned short hi = f2bf(v);
        wh[i] = hi;
        wl[i] = f2bf(v - bf2f(hi));
    }
}

// ===========================================================================
// Fused: QKV + attention (6 heads) + out-proj, one block per window.
// 768 threads (12 waves, 3/SIMD). LDS (shorts, total 63904 = 127808 B):
//   XF [kt6][tile9][512] @0      (27648)  -- x bf16 A-frags; reused as O-frags
//   Q2 [hl2][tile9][512] @27648  (9216)
//   K2 [hl2][tile9][512] @36864  (9216)
//   V2t[4][slab5][512]   @46080  (10240)  -- (hl*2+ntv) groups
//   P  [wv12][512]       @56320  (6144)   -- one k-slab per wave, reused 5x/unit
//   MB [144][5] u32      @62464  (1440 sh)
// Per-group work split (g = 2-head group):
//   QKV: 12 column-tiles -> 1/wave.  Attention: 18 units -> round1 all 12
//   waves, round2 waves 0-5.  Out-proj: 12 col-tiles -> 1/wave.
// ===========================================================================
__global__ __launch_bounds__(768, 3)
void fused(const float* __restrict__ x, const int* __restrict__ mask,
           const float* __restrict__ bias_pre,
           const unsigned short* __restrict__ wqh, const unsigned short* __restrict__ wql,
           const float* __restrict__ b_qkv,
           const unsigned short* __restrict__ woh_g, const unsigned short* __restrict__ wol_g,
           const float* __restrict__ b_out, float* __restrict__ out)
{
    __shared__ __align__(16) unsigned short lds[63904];
    const int XFo = 0, Q2o = 27648, K2o = 36864, V2o = 46080, Po = 56320, MBo = 62464;

    const int t = threadIdx.x;
    const int w = blockIdx.x;
    const int lane = t & 63, wv = t >> 6;   // wv in [0,12)
    const int c = lane & 15, q = lane >> 4;
    const float scale = 0.17677669529663687f;
    const float* xg = x + (size_t)w * NT * DIM;

    // ---- stage x -> XF bf16 A-frags (13824 dwords) ----
    {
        unsigned* XFd = (unsigned*)&lds[XFo];
        #pragma unroll
        for (int l = 0; l < 18; ++l) {
            int d = t + l * 768;
            int kt = d / 2304; int r2 = d - kt * 2304;
            int tile = r2 >> 8; int r3 = r2 & 255;
            int ln = r3 >> 2, pp = r3 & 3;
            int n = tile * 16 + (ln & 15);
            int k = kt * 32 + (ln >> 4) * 8 + pp * 2;
            float2 xv = *(const float2*)&xg[n * DIM + k];
            XFd[d] = (unsigned)f2bf(xv.x) | ((unsigned)f2bf(xv.y) << 16);
        }
    }
    // ---- zero pad: V2t tokens 144..159 (P pad handled per-unit) ----
    for (int e = t; e < 1024; e += 768) {
        int gi = e >> 8, l2 = 32 + ((e >> 3) & 31), pos = e & 7;
        lds[V2o + (gi * 5 + 4) * 512 + l2 * 8 + pos] = 0;
    }
    // ---- mask -> bit-packed MB via ballot (coalesced, read once per window) ----
    {
        unsigned* mb = (unsigned*)&lds[MBo];
        #pragma unroll 4
        for (int rr = 0; rr < 12; ++rr) {
            int n = wv * 12 + rr;
            const int* mrow = mask + ((size_t)w * NT + n) * NT;
            unsigned long long b0 = __ballot(mrow[lane] != 0);
            unsigned long long b1 = __ballot(mrow[64 + lane] != 0);
            int mv = (lane < 16) ? mrow[128 + lane] : 0;
            unsigned long long b2 = __ballot(mv != 0);
            if (lane == 0) {
                mb[n * 5 + 0] = (unsigned)b0;
                mb[n * 5 + 1] = (unsigned)(b0 >> 32);
                mb[n * 5 + 2] = (unsigned)b1;
                mb[n * 5 + 3] = (unsigned)(b1 >> 32);
                mb[n * 5 + 4] = (unsigned)b2;
            }
        }
    }

    const int hl   = wv / 6;        // phase-A head-in-group
    const int j6   = wv % 6;        // phase-A column-tile within head (0..5)
    const int part = j6 >> 1;       // 0=Q,1=K,2=V
    const int jj   = j6 & 1;        // which 16-col half of the 32-wide head dim
    const int hl2  = wv & 1;        // phase-B head-in-group
    const int sA   = wv >> 1;       // phase-B round-1 strip (0..5)

    floatx4 Oacc[3][2][2];

    // attention unit: strip s of head (2g+hl2); accumulates into O[2]
    auto attn_unit = [&](int g, int s, floatx4* O) {
        const int hB = 2 * g + hl2;
        // Issue all 36 bias loads up-front (L2 latency hides under QK MFMAs)
        float bb[4][9];
        const float* bbase = bias_pre + hB * (NT * NT) + (s * 16 + q * 4) * NT + c;
        #pragma unroll
        for (int r = 0; r < 4; ++r)
            #pragma unroll
            for (int nt = 0; nt < 9; ++nt)
                bb[r][nt] = bbase[r * NT + nt * 16];
        bf16x8 qf = *(const bf16x8*)&lds[Q2o + (hl2 * 9 + s) * 512 + lane * 8];
        floatx4 sacc[9];
        __builtin_amdgcn_s_setprio(1);
        #pragma unroll
        for (int nt = 0; nt < 9; ++nt) {
            bf16x8 kf = *(const bf16x8*)&lds[K2o + (hl2 * 9 + nt) * 512 + lane * 8];
            sacc[nt] = mfma16(qf, kf, (floatx4)0.0f);
        }
        __builtin_amdgcn_s_setprio(0);
        const unsigned* mb = (const unsigned*)&lds[MBo];
        unsigned mwv[4][5];
        #pragma unroll
        for (int r = 0; r < 4; ++r) {
            int n = s * 16 + q * 4 + r;
            #pragma unroll
            for (int k5 = 0; k5 < 5; ++k5) mwv[r][k5] = mb[n * 5 + k5];
        }
        // Batched softmax: 4 independent row-chains interleaved (4-way ILP on
        // the shfl reduce chains). Per-row operand order unchanged -> bit-
        // identical results.
        float e[4][9], mx[4];
        #pragma unroll
        for (int r = 0; r < 4; ++r) mx[r] = -1e30f;
        #pragma unroll
        for (int r = 0; r < 4; ++r)
            #pragma unroll
            for (int nt = 0; nt < 9; ++nt) {
                float val = sacc[nt][r] + bb[r][nt];
                unsigned bit = (mwv[r][nt >> 1] >> (((nt & 1) << 4) + c)) & 1u;
                val = bit ? val : -1e9f;
                e[r][nt] = val; mx[r] = fmaxf(mx[r], val);
            }
        #pragma unroll
        for (int o = 8; o; o >>= 1)
            #pragma unroll
            for (int r = 0; r < 4; ++r) mx[r] = fmaxf(mx[r], __shfl_xor(mx[r], o, 64));
        float sum[4] = {0.f, 0.f, 0.f, 0.f};
        #pragma unroll
        for (int r = 0; r < 4; ++r)
            #pragma unroll
            for (int nt = 0; nt < 9; ++nt) { e[r][nt] = __expf(e[r][nt] - mx[r]); sum[r] += e[r][nt]; }
        #pragma unroll
        for (int o = 8; o; o >>= 1)
            #pragma unroll
            for (int r = 0; r < 4; ++r) sum[r] += __shfl_xor(sum[r], o, 64);
        float rinv[4];
        #pragma unroll
        for (int r = 0; r < 4; ++r) rinv[r] = 1.0f / sum[r];
        // PV: per k-slab, write 16x32 P-slab -> read A-frag -> 2 MFMAs.
        // Slab 4 upper half (tokens 144..159) is zero-filled explicitly.
        // Fences on BOTH sides of the read: RAW (stores->read) and WAR
        // (read->next slab's stores) are invisible to TBAA.
        floatx4 o0 = (floatx4)0.0f, o1 = (floatx4)0.0f;
        unsigned short* pbase = &lds[Po + wv * 512];
        #pragma unroll
        for (int sl = 0; sl < 5; ++sl) {
            asm volatile("" ::: "memory");
            #pragma unroll
            for (int r = 0; r < 4; ++r)
                #pragma unroll
                for (int ntl = 0; ntl < 2; ++ntl) {
                    int nt = 2 * sl + ntl;
                    unsigned short pv = 0;
                    if (nt < 9) pv = f2bf(e[r][nt] * rinv[r]);
                    pbase[((q * 4 + r) + 16 * ((ntl << 1) + (c >> 3))) * 8 + (c & 7)] = pv;
                }
            asm volatile("" ::: "memory");
            bf16x8 pf = lds_ld8(&pbase[lane * 8]);
            __builtin_amdgcn_s_setprio(1);
            o0 = mfma16(pf, *(const bf16x8*)&lds[V2o + ((hl2 * 2 + 0) * 5 + sl) * 512 + lane * 8], o0);
            o1 = mfma16(pf, *(const bf16x8*)&lds[V2o + ((hl2 * 2 + 1) * 5 + sl) * 512 + lane * 8], o1);
            __builtin_amdgcn_s_setprio(0);
        }
        O[0] = o0; O[1] = o1;
    };

    #pragma unroll
    for (int g = 0; g < 3; ++g) {
        __syncthreads();            // XF/MB ready (g=0) / prev group's B reads done
        const int hg = 2 * g + hl;

        // hoisted B-frags (hi AND lo) for this wave's single column-tile
        const unsigned short* bhp = wqh + (size_t)((hg * 6 + j6) * 6) * 512 + lane * 8;
        const unsigned short* blp = wql + (size_t)((hg * 6 + j6) * 6) * 512 + lane * 8;
        bf16x8 bh[6], bl[6];
        #pragma unroll
        for (int kt = 0; kt < 6; ++kt) {
            bh[kt] = *(const bf16x8*)&bhp[kt * 512];
            bl[kt] = *(const bf16x8*)&blp[kt * 512];
        }
        float bq = b_qkv[part * DIM + hg * HD + jj * 16 + c];

        // ---- QKV gemm: this wave's 1 column-tile ----
        #pragma unroll
        for (int i3 = 0; i3 < 3; ++i3) {
            floatx4 a[3];
            #pragma unroll
            for (int ii = 0; ii < 3; ++ii) a[ii] = (floatx4)0.0f;
            __builtin_amdgcn_s_setprio(1);
            #pragma unroll
            for (int kt = 0; kt < 6; ++kt) {
                #pragma unroll
                for (int ii = 0; ii < 3; ++ii) {
                    bf16x8 ah = *(const bf16x8*)&lds[XFo + (kt * 9 + i3 * 3 + ii) * 512 + lane * 8];
                    a[ii] = mfma16(ah, bh[kt], a[ii]);
                    a[ii] = mfma16(ah, bl[kt], a[ii]);
                }
            }
            __builtin_amdgcn_s_setprio(0);
            // scatter C-layout -> frag layouts (unified col32 form of the
            // R3-verified formulas; col32 = jj*16 + c)
            #pragma unroll
            for (int ii = 0; ii < 3; ++ii) {
                int i = i3 * 3 + ii;
                #pragma unroll
                for (int r = 0; r < 4; ++r) {
                    float v = a[ii][r] + bq;
                    int col32 = jj * 16 + c;
                    if (part == 0) {
                        lds[Q2o + (hl * 9 + i) * 512 + ((q * 4 + r) + 16 * (col32 >> 3)) * 8 + (col32 & 7)] = f2bf(v * scale);
                    } else if (part == 1) {
                        lds[K2o + (hl * 9 + i) * 512 + ((q * 4 + r) + 16 * (col32 >> 3)) * 8 + (col32 & 7)] = f2bf(v);
                    } else {
                        int n = i * 16 + q * 4 + r;
                        lds[V2o + ((hl * 2 + jj) * 5 + (n >> 5)) * 512 + (c + 16 * ((n >> 3) & 3)) * 8 + (n & 7)] = f2bf(v);
                    }
                }
            }
        }
        __syncthreads();

        // ---- attention: round 1 all 12 waves, round 2 waves 0-5 ----
        attn_unit(g, sA, Oacc[g][0]);
        if (wv < 6) attn_unit(g, 6 + sA, Oacc[g][1]);
    }

    // ---- phase C: O C-layout -> A-frags in XF region (x no longer needed) ----
    #pragma unroll
    for (int g = 0; g < 3; ++g) {
        int hB = 2 * g + hl2;
        #pragma unroll
        for (int ntv = 0; ntv < 2; ++ntv)
            #pragma unroll
            for (int r = 0; r < 4; ++r)
                lds[XFo + (hB * 9 + sA) * 512 +
                    ((q * 4 + r) + 16 * (ntv * 2 + (c >> 3))) * 8 + (c & 7)] =
                    f2bf(Oacc[g][0][ntv][r]);
        if (wv < 6) {
            #pragma unroll
            for (int ntv = 0; ntv < 2; ++ntv)
                #pragma unroll
                for (int r = 0; r < 4; ++r)
                    lds[XFo + (hB * 9 + 6 + sA) * 512 +
                        ((q * 4 + r) + 16 * (ntv * 2 + (c >> 3))) * 8 + (c & 7)] =
                        f2bf(Oacc[g][1][ntv][r]);
        }
    }
    __syncthreads();

    // ---- out-proj: wave owns 1 output col-tile (colt = wv) ----
    {
        const unsigned short* whp = woh_g + (size_t)(wv * 6) * 512 + lane * 8;
        const unsigned short* wlp = wol_g + (size_t)(wv * 6) * 512 + lane * 8;
        bf16x8 wh[6], wlo[6];
        #pragma unroll
        for (int kt = 0; kt < 6; ++kt) {
            wh[kt]  = *(const bf16x8*)&whp[kt * 512];
            wlo[kt] = *(const bf16x8*)&wlp[kt * 512];
        }
        float bo = b_out[wv * 16 + c];
        #pragma unroll
        for (int i3 = 0; i3 < 3; ++i3) {
            floatx4 a2[3];
            #pragma unroll
            for (int ii = 0; ii < 3; ++ii) a2[ii] = (floatx4)0.0f;
            __builtin_amdgcn_s_setprio(1);
            #pragma unroll
            for (int kt = 0; kt < 6; ++kt) {
                #pragma unroll
                for (int ii = 0; ii < 3; ++ii) {
                    bf16x8 af = *(const bf16x8*)&lds[XFo + (kt * 9 + i3 * 3 + ii) * 512 + lane * 8];
                    a2[ii] = mfma16(af, wh[kt], a2[ii]);
                    a2[ii] = mfma16(af, wlo[kt], a2[ii]);
                }
            }
            __builtin_amdgcn_s_setprio(0);
            #pragma unroll
            for (int ii = 0; ii < 3; ++ii) {
                int n0 = (i3 * 3 + ii) * 16 + q * 4;
                #pragma unroll
                for (int r = 0; r < 4; ++r) {
                    size_t ro = ((size_t)w * NT + n0 + r) * DIM;
                    out[ro + wv * 16 + c] = a2[ii][r] + bo;
                }
            }
        }
    }
}

// ===========================================================================
// Zero-ws fallback (R1 fp32 kernels, verified)
// ===========================================================================
__global__ __launch_bounds__(256, 2)
void attn_kernel(const float* __restrict__ x, const int* __restrict__ mask,
                 const int* __restrict__ rel_index, const float* __restrict__ w_qkv,
                 const float* __restrict__ b_qkv, const float* __restrict__ bias_table,
                 float* __restrict__ out)
{
    __shared__ float smem[19136];
    float* xt = smem;
    float* wt = smem + 4768;
    float* qs = smem;
    float* ks = smem + 4752;
    float* vs = smem + 9504;
    float* S  = smem + 14400;

    const int t  = threadIdx.x;
    const int w  = blockIdx.x / NH;
    const int h  = blockIdx.x % NH;
    const int tx = t & 15;
    const int ty = t >> 4;
    const float scale = 0.17677669529663687f;
    const float* xg = x + (size_t)w * NT * DIM;

    float acc[9][6];
    #pragma unroll
    for (int i = 0; i < 9; ++i)
        #pragma unroll
        for (int j = 0; j < 6; ++j) acc[i][j] = 0.f;

    for (int kt = 0; kt < 6; ++kt) {
        #pragma unroll
        for (int l = 0; l < 18; ++l) {
            int e = t + l * 256;
            int n = e >> 5, kk = e & 31;
            xt[kk * 149 + n] = xg[n * DIM + kt * 32 + kk];
        }
        #pragma unroll
        for (int l = 0; l < 12; ++l) {
            int e = t + l * 256;
            int kk = e / 96, cc = e - kk * 96;
            int col = (cc >> 5) * DIM + h * HD + (cc & 31);
            wt[kk * 96 + cc] = w_qkv[(kt * 32 + kk) * WCOLS + col];
        }
        __syncthreads();
        #pragma unroll
        for (int kk = 0; kk < 32; ++kk) {
            float a[9], b[6];
            #pragma unroll
            for (int i = 0; i < 9; ++i) a[i] = xt[kk * 149 + ty * 9 + i];
            #pragma unroll
            for (int j = 0; j < 6; ++j) b[j] = wt[kk * 96 + tx * 6 + j];
            #pragma unroll
            for (int i = 0; i < 9; ++i)
                #pragma unroll
                for (int j = 0; j < 6; ++j) acc[i][j] = fmaf(a[i], b[j], acc[i][j]);
        }
        __syncthreads();
    }

    #pragma unroll
    for (int j = 0; j < 6; ++j) {
        int cc = tx * 6 + j;
        int part = cc >> 5, jj = cc & 31;
        float bq = b_qkv[part * DIM + h * HD + jj];
        #pragma unroll
        for (int i = 0; i < 9; ++i) {
            int r = ty * 9 + i;
            float val = acc[i][j] + bq;
            if (part == 0)      qs[r * 33 + jj] = val * scale;
            else if (part == 1) ks[r * 33 + jj] = val;
            else                vs[r * 34 + jj] = val;
        }
    }
    __syncthreads();

    const int wave = t >> 6, lane = t & 63;
    for (int rt = 0; rt < 5; ++rt) {
        const int rows = (rt == 4) ? 16 : 32;
        {
            int r0 = ty * 2;
            int n0 = rt * 32 + r0; if (n0 > NT - 1) n0 = NT - 1;
            int n1 = n0 + 1;       if (n1 > NT - 1) n1 = NT - 1;
            int m0 = tx * 9;
            float s0[9], s1[9];
            #pragma unroll
            for (int j = 0; j < 9; ++j) { s0[j] = 0.f; s1[j] = 0.f; }
            #pragma unroll
            for (int kk = 0; kk < 32; ++kk) {
                float a0 = qs[n0 * 33 + kk];
                float a1 = qs[n1 * 33 + kk];
                #pragma unroll
                for (int j = 0; j < 9; ++j) {
                    float bk = ks[(m0 + j) * 33 + kk];
                    s0[j] = fmaf(a0, bk, s0[j]);
                    s1[j] = fmaf(a1, bk, s1[j]);
                }
            }
            if (r0 < rows) {
                #pragma unroll
                for (int j = 0; j < 9; ++j) S[r0 * 148 + m0 + j] = s0[j];
                #pragma unroll
                for (int j = 0; j < 9; ++j) S[(r0 + 1) * 148 + m0 + j] = s1[j];
            }
        }
        __syncthreads();

        for (int r = wave; r < rows; r += 4) {
            int n = rt * 32 + r;
            const int* mrow = mask + ((size_t)w * NT + n) * NT;
            const int* rrow = rel_index + n * NT;
            float e0 = S[r * 148 + lane] + bias_table[rrow[lane] * NH + h];
            if (mrow[lane] == 0) e0 = -1e9f;
            float e1 = S[r * 148 + 64 + lane] + bias_table[rrow[64 + lane] * NH + h];
            if (mrow[64 + lane] == 0) e1 = -1e9f;
            float e2 = -INFINITY;
            if (lane < 16) {
                e2 = S[r * 148 + 128 + lane] + bias_table[rrow[128 + lane] * NH + h];
                if (mrow[128 + lane] == 0) e2 = -1e9f;
            }
            float vmax = fmaxf(fmaxf(e0, e1), e2);
            #pragma unroll
            for (int off = 32; off > 0; off >>= 1)
                vmax = fmaxf(vmax, __shfl_xor(vmax, off, 64));
            float p0 = __expf(e0 - vmax);
            float p1 = __expf(e1 - vmax);
            float p2 = (lane < 16) ? __expf(e2 - vmax) : 0.f;
            float s = p0 + p1 + p2;
            #pragma unroll
            for (int off = 32; off > 0; off >>= 1)
                s += __shfl_xor(s, off, 64);
            float rinv = 1.f / s;
            S[r * 148 + lane] = p0 * rinv;
            S[r * 148 + 64 + lane] = p1 * rinv;
            if (lane < 16) S[r * 148 + 128 + lane] = p2 * rinv;
        }
        __syncthreads();

        {
            int r0 = ty * 2, dd0 = tx * 2;
            if (r0 < rows) {
                float o00 = 0, o01 = 0, o10 = 0, o11 = 0;
                #pragma unroll
                for (int m = 0; m < NT; ++m) {
                    float p0 = S[r0 * 148 + m];
                    float p1 = S[(r0 + 1) * 148 + m];
                    float2 vv = *(const float2*)&vs[m * 34 + dd0];
                    o00 = fmaf(p0, vv.x, o00);
                    o01 = fmaf(p0, vv.y, o01);
                    o10 = fmaf(p1, vv.x, o10);
                    o11 = fmaf(p1, vv.y, o11);
                }
                int n0 = rt * 32 + r0;
                *(float2*)&out[((size_t)(w * NT + n0)) * DIM + h * HD + dd0] = make_float2(o00, o01);
                *(float2*)&out[((size_t)(w * NT + n0 + 1)) * DIM + h * HD + dd0] = make_float2(o10, o11);
            }
        }
        __syncthreads();
    }
}

__global__ __launch_bounds__(256, 2)
void proj_kernel(float* __restrict__ io, const float* __restrict__ w_out,
                 const float* __restrict__ b_out)
{
    __shared__ float in_t[64 * 196];
    __shared__ float wt[32 * 192];
    const int t = threadIdx.x;
    const size_t row0 = (size_t)blockIdx.x * 64;

    #pragma unroll
    for (int l = 0; l < 12; ++l) {
        int e = t + l * 256;
        int r = e / 48, c4 = e - r * 48;
        float4 val = *(const float4*)&io[(row0 + r) * DIM + c4 * 4];
        *(float4*)&in_t[r * 196 + c4 * 4] = val;
    }
    const int tx = t & 15, ty = t >> 4;
    float acc[4][12];
    #pragma unroll
    for (int i = 0; i < 4; ++i)
        #pragma unroll
        for (int j = 0; j < 12; ++j) acc[i][j] = 0.f;

    for (int kt = 0; kt < 6; ++kt) {
        __syncthreads();
        #pragma unroll
        for (int l = 0; l < 6; ++l) {
            int e = t + l * 256;
            int kk = e / 48, c4 = e - kk * 48;
            *(float4*)&wt[kk * 192 + c4 * 4] =
                *(const float4*)&w_out[(kt * 32 + kk) * DIM + c4 * 4];
        }
        __syncthreads();
        #pragma unroll
        for (int kk = 0; kk < 32; ++kk) {
            float a[4];
            #pragma unroll
            for (int i = 0; i < 4; ++i) a[i] = in_t[(ty * 4 + i) * 196 + kt * 32 + kk];
            float b[12];
            #pragma unroll
            for (int j4 = 0; j4 < 3; ++j4) {
                float4 bb = *(const float4*)&wt[kk * 192 + tx * 12 + j4 * 4];
                b[j4 * 4] = bb.x; b[j4 * 4 + 1] = bb.y;
                b[j4 * 4 + 2] = bb.z; b[j4 * 4 + 3] = bb.w;
            }
            #pragma unroll
            for (int i = 0; i < 4; ++i)
                #pragma unroll
                for (int j = 0; j < 12; ++j)
                    acc[i][j] = fmaf(a[i], b[j], acc[i][j]);
        }
    }

    float bo[12];
    #pragma unroll
    for (int j4 = 0; j4 < 3; ++j4) {
        float4 bb = *(const float4*)&b_out[tx * 12 + j4 * 4];
        bo[j4 * 4] = bb.x; bo[j4 * 4 + 1] = bb.y;
        bo[j4 * 4 + 2] = bb.z; bo[j4 * 4 + 3] = bb.w;
    }
    #pragma unroll
    for (int i = 0; i < 4; ++i) {
        size_t r = row0 + ty * 4 + i;
        #pragma unroll
        for (int j4 = 0; j4 < 3; ++j4) {
            float4 o;
            o.x = acc[i][j4 * 4]     + bo[j4 * 4];
            o.y = acc[i][j4 * 4 + 1] + bo[j4 * 4 + 1];
            o.z = acc[i][j4 * 4 + 2] + bo[j4 * 4 + 2];
            o.w = acc[i][j4 * 4 + 3] + bo[j4 * 4 + 3];
            *(float4*)&io[r * DIM + tx * 12 + j4 * 4] = o;
        }
    }
}

// ===========================================================================
extern "C" void kernel_launch(void* const* d_in, const int* in_sizes, int n_in,
                              void* d_out, int out_size, void* d_ws, size_t ws_size,
                              hipStream_t stream) {
    const float* x          = (const float*)d_in[0];
    const int*   mask       = (const int*)d_in[1];
    const int*   rel_index  = (const int*)d_in[2];
    const float* w_qkv      = (const float*)d_in[3];
    const float* b_qkv      = (const float*)d_in[4];
    const float* w_out      = (const float*)d_in[5];
    const float* b_out      = (const float*)d_in[6];
    const float* bias_table = (const float*)d_in[7];
    float* out = (float*)d_out;

    // ws layout (bytes):
    //   bias_pre @0        : 497664
    //   wq_h     @497664   : 221184   (frag layout)
    //   wq_l     @718848   : 221184
    //   wo_h     @940032   :  73728   (frag layout)
    //   wo_l     @1013760  :  73728   -> total 1087488
    const size_t WS_NEED = 1087488;

    if (ws_size >= WS_NEED) {
        char* ws = (char*)d_ws;
        float*          bias_pre = (float*)ws;
        unsigned short* wq_h     = (unsigned short*)(ws + 497664);
        unsigned short* wq_l     = (unsigned short*)(ws + 718848);
        unsigned short* wo_h     = (unsigned short*)(ws + 940032);
        unsigned short* wo_l     = (unsigned short*)(ws + 1013760);

        hipLaunchKernelGGL(prep_bias, dim3(486), dim3(256), 0, stream,
                           rel_index, bias_table, bias_pre);
        hipLaunchKernelGGL(prep_wq_frag, dim3(432), dim3(256), 0, stream,
                           w_qkv, wq_h, wq_l);
        hipLaunchKernelGGL(prep_wo_frag, dim3(144), dim3(256), 0, stream,
                           w_out, wo_h, wo_l);
        hipLaunchKernelGGL(fused, dim3(NW), dim3(768), 0, stream,
                           x, mask, bias_pre, wq_h, wq_l, b_qkv,
                           wo_h, wo_l, b_out, out);
    } else {
        hipLaunchKernelGGL(attn_kernel, dim3(NW * NH), dim3(256), 0, stream,
                           x, mask, rel_index, w_qkv, b_qkv, bias_table, out);
        hipLaunchKernelGGL(proj_kernel, dim3(NW * NT / 64), dim3(256), 0, stream,
                           out, w_out, b_out);
    }
}

// Round 5
// 451.450 us; speedup vs baseline: 1.2621x; 1.0995x over previous
//
#include <hip/hip_runtime.h>
#include <math.h>

#define NW 960
#define NT 144
#define DIM 192
#define NH 6
#define HD 32
#define WCOLS 576

typedef __bf16 bf16x8 __attribute__((ext_vector_type(8)));
typedef float floatx4 __attribute__((ext_vector_type(4)));

__device__ __forceinline__ unsigned short f2bf(float x) {
    union { float f; unsigned u; } v; v.f = x;
    unsigned r = v.u + 0x7fffu + ((v.u >> 16) & 1u);
    return (unsigned short)(r >> 16);
}
__device__ __forceinline__ float bf2f(unsigned short b) {
    union { unsigned u; float f; } v; v.u = ((unsigned)b) << 16;
    return v.f;
}
__device__ __forceinline__ floatx4 mfma16(bf16x8 a, bf16x8 b, floatx4 c) {
    return __builtin_amdgcn_mfma_f32_16x16x32_bf16(a, b, c, 0, 0, 0);
}
// Aliasing-safe LDS vector load: used where a bf16x8 read must not be
// reordered above preceding unsigned-short stores to the same region
// (TBAA would otherwise allow the hoist - the P tile is the only LDS
// RAW seam not protected by __syncthreads()).
__device__ __forceinline__ bf16x8 lds_ld8(const unsigned short* p) {
    bf16x8 v;
    __builtin_memcpy(&v, p, 16);
    return v;
}

// ===========================================================================
// Prep kernels (tiny; weights + bias only)
// ===========================================================================
__global__ void prep_bias(const int* __restrict__ rel_index,
                          const float* __restrict__ bias_table,
                          float* __restrict__ bias_pre) {
    int i = blockIdx.x * 256 + threadIdx.x;           // [6][144][144]
    if (i < NH * NT * NT) {
        int h = i / (NT * NT);
        int rem = i - h * (NT * NT);
        bias_pre[i] = bias_table[rel_index[rem] * NH + h];
    }
}

// wq frag: [h][j(6)][kt(6)][lane(64)][pos(8)]
__global__ void prep_wq_frag(const float* __restrict__ w_qkv,
                             unsigned short* __restrict__ wh,
                             unsigned short* __restrict__ wl) {
    int i = blockIdx.x * 256 + threadIdx.x;           // 6*6*6*512 = 110592
    if (i < NH * 6 * 6 * 512) {
        int h = i / 18432; int r = i - h * 18432;
        int j = r / 3072;  r -= j * 3072;
        int kt = r / 512;  r -= kt * 512;
        int lane = r >> 3, pos = r & 7;
        int col96 = j * 16 + (lane & 15);
        int k = kt * 32 + (lane >> 4) * 8 + pos;
        float v = w_qkv[k * WCOLS + (col96 >> 5) * DIM + h * HD + (col96 & 31)];
        unsigned short hi = f2bf(v);
        wh[i] = hi;
        wl[i] = f2bf(v - bf2f(hi));
    }
}

// wout frag: [nt(12)][kt(6)][lane(64)][pos(8)]
__global__ void prep_wo_frag(const float* __restrict__ w_out,
                             unsigned short* __restrict__ wh,
                             unsigned short* __restrict__ wl) {
    int i = blockIdx.x * 256 + threadIdx.x;           // 12*6*512 = 36864
    if (i < 12 * 6 * 512) {
        int nt = i / 3072; int r = i - nt * 3072;
        int kt = r / 512;  r -= kt * 512;
        int lane = r >> 3, pos = r & 7;
        int ocol = nt * 16 + (lane & 15);
        int k = kt * 32 + (lane >> 4) * 8 + pos;
        float v = w_out[k * DIM + ocol];
        unsigned short hi = f2bf(v);
        wh[i] = hi;
        wl[i] = f2bf(v - bf2f(hi));
    }
}

// ===========================================================================
// Fused: QKV + attention + out-proj, one block per window, SOFTWARE-PIPELINED
// across heads: region R_h = { attn(h-1) || QKV(h) } with double-buffered
// per-head Q/K/V sets (alternating parity) -> one barrier per head.
// 768 threads (12 waves, 3/SIMD). LDS (shorts, total 63904 = 127808 B):
//   XF  [kt6][tile9][512] @0     (27648)  -- x bf16 A-frags; reused as O-frags
//   BUF0/BUF1 per-head QKV sets  @27648, @41984 (14336 each):
//       Q2 [tile9][512] +0, K2 [tile9][512] +4608, V2t [ntv2][slab5][512] +9216
//   P   [wv12][512]       @56320 (6144)   -- per-wave slab, reused 5x/unit
//   MB  [144][5] u32      @62464 (1440 sh)
// Work split per region: waves 0-8: attn unit (strip=wv) + QKV sub-tile
// (j=wv/3, i3=wv%3); waves 9-11: 1 full QKV tile (j=3+wv-9).
// Races: QKV(h) writes buf[h&1], attn(h-1) reads buf[(h-1)&1] -> disjoint;
// buffer reuse always crosses >=1 barrier.
// ===========================================================================
__global__ __launch_bounds__(768, 3)
void fused(const float* __restrict__ x, const int* __restrict__ mask,
           const float* __restrict__ bias_pre,
           const unsigned short* __restrict__ wqh, const unsigned short* __restrict__ wql,
           const float* __restrict__ b_qkv,
           const unsigned short* __restrict__ woh_g, const unsigned short* __restrict__ wol_g,
           const float* __restrict__ b_out, float* __restrict__ out)
{
    __shared__ __align__(16) unsigned short lds[63904];
    const int XFo = 0;
    const int BUF0 = 27648, BUFSZ = 14336;
    const int Q2off = 0, K2off = 4608, V2off = 9216;
    const int Po = 56320, MBo = 62464;

    const int t = threadIdx.x;
    const int w = blockIdx.x;
    const int lane = t & 63, wv = t >> 6;   // wv in [0,12)
    const int c = lane & 15, q = lane >> 4;
    const float scale = 0.17677669529663687f;
    const float* xg = x + (size_t)w * NT * DIM;

    // ---- stage x -> XF bf16 A-frags (13824 dwords) ----
    {
        unsigned* XFd = (unsigned*)&lds[XFo];
        #pragma unroll
        for (int l = 0; l < 18; ++l) {
            int d = t + l * 768;
            int kt = d / 2304; int r2 = d - kt * 2304;
            int tile = r2 >> 8; int r3 = r2 & 255;
            int ln = r3 >> 2, pp = r3 & 3;
            int n = tile * 16 + (ln & 15);
            int k = kt * 32 + (ln >> 4) * 8 + pp * 2;
            float2 xv = *(const float2*)&xg[n * DIM + k];
            XFd[d] = (unsigned)f2bf(xv.x) | ((unsigned)f2bf(xv.y) << 16);
        }
    }
    // ---- zero pad: V2t tokens 144..159 in BOTH buffers ----
    for (int e = t; e < 1024; e += 768) {
        int b = e >> 9, r2 = e & 511;
        int gi = r2 >> 8, l2 = 32 + ((r2 >> 3) & 31), pos = r2 & 7;
        lds[BUF0 + b * BUFSZ + V2off + (gi * 5 + 4) * 512 + l2 * 8 + pos] = 0;
    }
    // ---- mask -> bit-packed MB via ballot (coalesced, read once per window) ----
    {
        unsigned* mb = (unsigned*)&lds[MBo];
        #pragma unroll 4
        for (int rr = 0; rr < 12; ++rr) {
            int n = wv * 12 + rr;
            const int* mrow = mask + ((size_t)w * NT + n) * NT;
            unsigned long long b0 = __ballot(mrow[lane] != 0);
            unsigned long long b1 = __ballot(mrow[64 + lane] != 0);
            int mv = (lane < 16) ? mrow[128 + lane] : 0;
            unsigned long long b2 = __ballot(mv != 0);
            if (lane == 0) {
                mb[n * 5 + 0] = (unsigned)b0;
                mb[n * 5 + 1] = (unsigned)(b0 >> 32);
                mb[n * 5 + 2] = (unsigned)b1;
                mb[n * 5 + 3] = (unsigned)(b1 >> 32);
                mb[n * 5 + 4] = (unsigned)b2;
            }
        }
    }

    // ---- QKV tile worker: head h, column-tile j, i3 range [i3lo, i3lo+i3n) ----
    auto qkv_tile = [&](int h, int j, int i3lo, int i3n) {
        const int part = j >> 1, jj = j & 1;
        unsigned short* buf = &lds[BUF0 + (h & 1) * BUFSZ];
        const unsigned short* bhp = wqh + (size_t)((h * 6 + j) * 6) * 512 + lane * 8;
        const unsigned short* blp = wql + (size_t)((h * 6 + j) * 6) * 512 + lane * 8;
        bf16x8 bh[6], bl[6];
        #pragma unroll
        for (int kt = 0; kt < 6; ++kt) {
            bh[kt] = *(const bf16x8*)&bhp[kt * 512];
            bl[kt] = *(const bf16x8*)&blp[kt * 512];
        }
        float bq = b_qkv[part * DIM + h * HD + jj * 16 + c];
        for (int i3x = 0; i3x < i3n; ++i3x) {
            int i3 = i3lo + i3x;
            floatx4 a[3];
            #pragma unroll
            for (int ii = 0; ii < 3; ++ii) a[ii] = (floatx4)0.0f;
            __builtin_amdgcn_s_setprio(1);
            #pragma unroll
            for (int kt = 0; kt < 6; ++kt) {
                #pragma unroll
                for (int ii = 0; ii < 3; ++ii) {
                    bf16x8 ah = *(const bf16x8*)&lds[XFo + (kt * 9 + i3 * 3 + ii) * 512 + lane * 8];
                    a[ii] = mfma16(ah, bh[kt], a[ii]);
                    a[ii] = mfma16(ah, bl[kt], a[ii]);
                }
            }
            __builtin_amdgcn_s_setprio(0);
            // scatter C-layout -> frag layouts (R3-verified formulas, col32 form)
            #pragma unroll
            for (int ii = 0; ii < 3; ++ii) {
                int i = i3 * 3 + ii;
                #pragma unroll
                for (int r = 0; r < 4; ++r) {
                    float v = a[ii][r] + bq;
                    int col32 = jj * 16 + c;
                    if (part == 0) {
                        buf[Q2off + i * 512 + ((q * 4 + r) + 16 * (col32 >> 3)) * 8 + (col32 & 7)] = f2bf(v * scale);
                    } else if (part == 1) {
                        buf[K2off + i * 512 + ((q * 4 + r) + 16 * (col32 >> 3)) * 8 + (col32 & 7)] = f2bf(v);
                    } else {
                        int n = i * 16 + q * 4 + r;
                        buf[V2off + (jj * 5 + (n >> 5)) * 512 + (c + 16 * ((n >> 3) & 3)) * 8 + (n & 7)] = f2bf(v);
                    }
                }
            }
        }
    };

    // ---- attention unit: head h, strip s = wv; accumulates into O[2] ----
    auto attn_unit = [&](int h, floatx4 (&O)[2]) {
        const int s = wv;
        unsigned short* buf = &lds[BUF0 + (h & 1) * BUFSZ];
        // Issue all 36 bias loads up-front (L2 latency hides under QK MFMAs)
        float bb[4][9];
        const float* bbase = bias_pre + h * (NT * NT) + (s * 16 + q * 4) * NT + c;
        #pragma unroll
        for (int r = 0; r < 4; ++r)
            #pragma unroll
            for (int nt = 0; nt < 9; ++nt)
                bb[r][nt] = bbase[r * NT + nt * 16];
        bf16x8 qf = *(const bf16x8*)&buf[Q2off + s * 512 + lane * 8];
        floatx4 sacc[9];
        __builtin_amdgcn_s_setprio(1);
        #pragma unroll
        for (int nt = 0; nt < 9; ++nt) {
            bf16x8 kf = *(const bf16x8*)&buf[K2off + nt * 512 + lane * 8];
            sacc[nt] = mfma16(qf, kf, (floatx4)0.0f);
        }
        __builtin_amdgcn_s_setprio(0);
        const unsigned* mb = (const unsigned*)&lds[MBo];
        unsigned mwv[4][5];
        #pragma unroll
        for (int r = 0; r < 4; ++r) {
            int n = s * 16 + q * 4 + r;
            #pragma unroll
            for (int k5 = 0; k5 < 5; ++k5) mwv[r][k5] = mb[n * 5 + k5];
        }
        // Batched softmax: 4 independent row-chains interleaved (4-way ILP on
        // the shfl reduce chains). Per-row operand order unchanged -> bit-
        // identical results.
        float e[4][9], mx[4];
        #pragma unroll
        for (int r = 0; r < 4; ++r) mx[r] = -1e30f;
        #pragma unroll
        for (int r = 0; r < 4; ++r)
            #pragma unroll
            for (int nt = 0; nt < 9; ++nt) {
                float val = sacc[nt][r] + bb[r][nt];
                unsigned bit = (mwv[r][nt >> 1] >> (((nt & 1) << 4) + c)) & 1u;
                val = bit ? val : -1e9f;
                e[r][nt] = val; mx[r] = fmaxf(mx[r], val);
            }
        #pragma unroll
        for (int o = 8; o; o >>= 1)
            #pragma unroll
            for (int r = 0; r < 4; ++r) mx[r] = fmaxf(mx[r], __shfl_xor(mx[r], o, 64));
        float sum[4] = {0.f, 0.f, 0.f, 0.f};
        #pragma unroll
        for (int r = 0; r < 4; ++r)
            #pragma unroll
            for (int nt = 0; nt < 9; ++nt) { e[r][nt] = __expf(e[r][nt] - mx[r]); sum[r] += e[r][nt]; }
        #pragma unroll
        for (int o = 8; o; o >>= 1)
            #pragma unroll
            for (int r = 0; r < 4; ++r) sum[r] += __shfl_xor(sum[r], o, 64);
        float rinv[4];
        #pragma unroll
        for (int r = 0; r < 4; ++r) rinv[r] = 1.0f / sum[r];
        // PV: per k-slab, write 16x32 P-slab -> read A-frag -> 2 MFMAs.
        // Slab 4 upper half (tokens 144..159) zero-filled via pv=0.
        // Fences on BOTH sides of the read: RAW and WAR invisible to TBAA.
        floatx4 o0 = (floatx4)0.0f, o1 = (floatx4)0.0f;
        unsigned short* pbase = &lds[Po + wv * 512];
        #pragma unroll
        for (int sl = 0; sl < 5; ++sl) {
            asm volatile("" ::: "memory");
            #pragma unroll
            for (int r = 0; r < 4; ++r)
                #pragma unroll
                for (int ntl = 0; ntl < 2; ++ntl) {
                    int nt = 2 * sl + ntl;
                    unsigned short pv = 0;
                    if (nt < 9) pv = f2bf(e[r][nt] * rinv[r]);
                    pbase[((q * 4 + r) + 16 * ((ntl << 1) + (c >> 3))) * 8 + (c & 7)] = pv;
                }
            asm volatile("" ::: "memory");
            bf16x8 pf = lds_ld8(&pbase[lane * 8]);
            __builtin_amdgcn_s_setprio(1);
            o0 = mfma16(pf, *(const bf16x8*)&buf[V2off + (0 * 5 + sl) * 512 + lane * 8], o0);
            o1 = mfma16(pf, *(const bf16x8*)&buf[V2off + (1 * 5 + sl) * 512 + lane * 8], o1);
            __builtin_amdgcn_s_setprio(0);
        }
        O[0] = o0; O[1] = o1;
    };

    floatx4 Oacc[6][2];   // waves 0-8 only

    __syncthreads();      // B0: stage/pads/MB complete

    // R0: QKV(0) only
    if (wv < 9) qkv_tile(0, wv / 3, wv % 3, 1);
    else        qkv_tile(0, 3 + (wv - 9), 0, 3);

    // R1..R5: attn(h-1) || QKV(h)
    #pragma unroll
    for (int h = 1; h < 6; ++h) {
        __syncthreads();
        if (wv < 9) {
            attn_unit(h - 1, Oacc[h - 1]);
            qkv_tile(h, wv / 3, wv % 3, 1);
        } else {
            qkv_tile(h, 3 + (wv - 9), 0, 3);
        }
    }

    // R6: attn(5) + phase C (O -> A-frags in XF; XF's last reader was QKV(5))
    __syncthreads();
    if (wv < 9) {
        attn_unit(5, Oacc[5]);
        #pragma unroll
        for (int h = 0; h < 6; ++h)
            #pragma unroll
            for (int ntv = 0; ntv < 2; ++ntv)
                #pragma unroll
                for (int r = 0; r < 4; ++r)
                    lds[XFo + (h * 9 + wv) * 512 +
                        ((q * 4 + r) + 16 * (ntv * 2 + (c >> 3))) * 8 + (c & 7)] =
                        f2bf(Oacc[h][ntv][r]);
    }
    __syncthreads();

    // ---- out-proj: wave owns 1 output col-tile (colt = wv) ----
    {
        const unsigned short* whp = woh_g + (size_t)(wv * 6) * 512 + lane * 8;
        const unsigned short* wlp = wol_g + (size_t)(wv * 6) * 512 + lane * 8;
        bf16x8 wh[6], wlo[6];
        #pragma unroll
        for (int kt = 0; kt < 6; ++kt) {
            wh[kt]  = *(const bf16x8*)&whp[kt * 512];
            wlo[kt] = *(const bf16x8*)&wlp[kt * 512];
        }
        float bo = b_out[wv * 16 + c];
        #pragma unroll
        for (int i3 = 0; i3 < 3; ++i3) {
            floatx4 a2[3];
            #pragma unroll
            for (int ii = 0; ii < 3; ++ii) a2[ii] = (floatx4)0.0f;
            __builtin_amdgcn_s_setprio(1);
            #pragma unroll
            for (int kt = 0; kt < 6; ++kt) {
                #pragma unroll
                for (int ii = 0; ii < 3; ++ii) {
                    bf16x8 af = *(const bf16x8*)&lds[XFo + (kt * 9 + i3 * 3 + ii) * 512 + lane * 8];
                    a2[ii] = mfma16(af, wh[kt], a2[ii]);
                    a2[ii] = mfma16(af, wlo[kt], a2[ii]);
                }
            }
            __builtin_amdgcn_s_setprio(0);
            #pragma unroll
            for (int ii = 0; ii < 3; ++ii) {
                int n0 = (i3 * 3 + ii) * 16 + q * 4;
                #pragma unroll
                for (int r = 0; r < 4; ++r) {
                    size_t ro = ((size_t)w * NT + n0 + r) * DIM;
                    out[ro + wv * 16 + c] = a2[ii][r] + bo;
                }
            }
        }
    }
}

// ===========================================================================
// Zero-ws fallback (R1 fp32 kernels, verified)
// ===========================================================================
__global__ __launch_bounds__(256, 2)
void attn_kernel(const float* __restrict__ x, const int* __restrict__ mask,
                 const int* __restrict__ rel_index, const float* __restrict__ w_qkv,
                 const float* __restrict__ b_qkv, const float* __restrict__ bias_table,
                 float* __restrict__ out)
{
    __shared__ float smem[19136];
    float* xt = smem;
    float* wt = smem + 4768;
    float* qs = smem;
    float* ks = smem + 4752;
    float* vs = smem + 9504;
    float* S  = smem + 14400;

    const int t  = threadIdx.x;
    const int w  = blockIdx.x / NH;
    const int h  = blockIdx.x % NH;
    const int tx = t & 15;
    const int ty = t >> 4;
    const float scale = 0.17677669529663687f;
    const float* xg = x + (size_t)w * NT * DIM;

    float acc[9][6];
    #pragma unroll
    for (int i = 0; i < 9; ++i)
        #pragma unroll
        for (int j = 0; j < 6; ++j) acc[i][j] = 0.f;

    for (int kt = 0; kt < 6; ++kt) {
        #pragma unroll
        for (int l = 0; l < 18; ++l) {
            int e = t + l * 256;
            int n = e >> 5, kk = e & 31;
            xt[kk * 149 + n] = xg[n * DIM + kt * 32 + kk];
        }
        #pragma unroll
        for (int l = 0; l < 12; ++l) {
            int e = t + l * 256;
            int kk = e / 96, cc = e - kk * 96;
            int col = (cc >> 5) * DIM + h * HD + (cc & 31);
            wt[kk * 96 + cc] = w_qkv[(kt * 32 + kk) * WCOLS + col];
        }
        __syncthreads();
        #pragma unroll
        for (int kk = 0; kk < 32; ++kk) {
            float a[9], b[6];
            #pragma unroll
            for (int i = 0; i < 9; ++i) a[i] = xt[kk * 149 + ty * 9 + i];
            #pragma unroll
            for (int j = 0; j < 6; ++j) b[j] = wt[kk * 96 + tx * 6 + j];
            #pragma unroll
            for (int i = 0; i < 9; ++i)
                #pragma unroll
                for (int j = 0; j < 6; ++j) acc[i][j] = fmaf(a[i], b[j], acc[i][j]);
        }
        __syncthreads();
    }

    #pragma unroll
    for (int j = 0; j < 6; ++j) {
        int cc = tx * 6 + j;
        int part = cc >> 5, jj = cc & 31;
        float bq = b_qkv[part * DIM + h * HD + jj];
        #pragma unroll
        for (int i = 0; i < 9; ++i) {
            int r = ty * 9 + i;
            float val = acc[i][j] + bq;
            if (part == 0)      qs[r * 33 + jj] = val * scale;
            else if (part == 1) ks[r * 33 + jj] = val;
            else                vs[r * 34 + jj] = val;
        }
    }
    __syncthreads();

    const int wave = t >> 6, lane = t & 63;
    for (int rt = 0; rt < 5; ++rt) {
        const int rows = (rt == 4) ? 16 : 32;
        {
            int r0 = ty * 2;
            int n0 = rt * 32 + r0; if (n0 > NT - 1) n0 = NT - 1;
            int n1 = n0 + 1;       if (n1 > NT - 1) n1 = NT - 1;
            int m0 = tx * 9;
            float s0[9], s1[9];
            #pragma unroll
            for (int j = 0; j < 9; ++j) { s0[j] = 0.f; s1[j] = 0.f; }
            #pragma unroll
            for (int kk = 0; kk < 32; ++kk) {
                float a0 = qs[n0 * 33 + kk];
                float a1 = qs[n1 * 33 + kk];
                #pragma unroll
                for (int j = 0; j < 9; ++j) {
                    float bk = ks[(m0 + j) * 33 + kk];
                    s0[j] = fmaf(a0, bk, s0[j]);
                    s1[j] = fmaf(a1, bk, s1[j]);
                }
            }
            if (r0 < rows) {
                #pragma unroll
                for (int j = 0; j < 9; ++j) S[r0 * 148 + m0 + j] = s0[j];
                #pragma unroll
                for (int j = 0; j < 9; ++j) S[(r0 + 1) * 148 + m0 + j] = s1[j];
            }
        }
        __syncthreads();

        for (int r = wave; r < rows; r += 4) {
            int n = rt * 32 + r;
            const int* mrow = mask + ((size_t)w * NT + n) * NT;
            const int* rrow = rel_index + n * NT;
            float e0 = S[r * 148 + lane] + bias_table[rrow[lane] * NH + h];
            if (mrow[lane] == 0) e0 = -1e9f;
            float e1 = S[r * 148 + 64 + lane] + bias_table[rrow[64 + lane] * NH + h];
            if (mrow[64 + lane] == 0) e1 = -1e9f;
            float e2 = -INFINITY;
            if (lane < 16) {
                e2 = S[r * 148 + 128 + lane] + bias_table[rrow[128 + lane] * NH + h];
                if (mrow[128 + lane] == 0) e2 = -1e9f;
            }
            float vmax = fmaxf(fmaxf(e0, e1), e2);
            #pragma unroll
            for (int off = 32; off > 0; off >>= 1)
                vmax = fmaxf(vmax, __shfl_xor(vmax, off, 64));
            float p0 = __expf(e0 - vmax);
            float p1 = __expf(e1 - vmax);
            float p2 = (lane < 16) ? __expf(e2 - vmax) : 0.f;
            float s = p0 + p1 + p2;
            #pragma unroll
            for (int off = 32; off > 0; off >>= 1)
                s += __shfl_xor(s, off, 64);
            float rinv = 1.f / s;
            S[r * 148 + lane] = p0 * rinv;
            S[r * 148 + 64 + lane] = p1 * rinv;
            if (lane < 16) S[r * 148 + 128 + lane] = p2 * rinv;
        }
        __syncthreads();

        {
            int r0 = ty * 2, dd0 = tx * 2;
            if (r0 < rows) {
                float o00 = 0, o01 = 0, o10 = 0, o11 = 0;
                #pragma unroll
                for (int m = 0; m < NT; ++m) {
                    float p0 = S[r0 * 148 + m];
                    float p1 = S[(r0 + 1) * 148 + m];
                    float2 vv = *(const float2*)&vs[m * 34 + dd0];
                    o00 = fmaf(p0, vv.x, o00);
                    o01 = fmaf(p0, vv.y, o01);
                    o10 = fmaf(p1, vv.x, o10);
                    o11 = fmaf(p1, vv.y, o11);
                }
                int n0 = rt * 32 + r0;
                *(float2*)&out[((size_t)(w * NT + n0)) * DIM + h * HD + dd0] = make_float2(o00, o01);
                *(float2*)&out[((size_t)(w * NT + n0 + 1)) * DIM + h * HD + dd0] = make_float2(o10, o11);
            }
        }
        __syncthreads();
    }
}

__global__ __launch_bounds__(256, 2)
void proj_kernel(float* __restrict__ io, const float* __restrict__ w_out,
                 const float* __restrict__ b_out)
{
    __shared__ float in_t[64 * 196];
    __shared__ float wt[32 * 192];
    const int t = threadIdx.x;
    const size_t row0 = (size_t)blockIdx.x * 64;

    #pragma unroll
    for (int l = 0; l < 12; ++l) {
        int e = t + l * 256;
        int r = e / 48, c4 = e - r * 48;
        float4 val = *(const float4*)&io[(row0 + r) * DIM + c4 * 4];
        *(float4*)&in_t[r * 196 + c4 * 4] = val;
    }
    const int tx = t & 15, ty = t >> 4;
    float acc[4][12];
    #pragma unroll
    for (int i = 0; i < 4; ++i)
        #pragma unroll
        for (int j = 0; j < 12; ++j) acc[i][j] = 0.f;

    for (int kt = 0; kt < 6; ++kt) {
        __syncthreads();
        #pragma unroll
        for (int l = 0; l < 6; ++l) {
            int e = t + l * 256;
            int kk = e / 48, c4 = e - kk * 48;
            *(float4*)&wt[kk * 192 + c4 * 4] =
                *(const float4*)&w_out[(kt * 32 + kk) * DIM + c4 * 4];
        }
        __syncthreads();
        #pragma unroll
        for (int kk = 0; kk < 32; ++kk) {
            float a[4];
            #pragma unroll
            for (int i = 0; i < 4; ++i) a[i] = in_t[(ty * 4 + i) * 196 + kt * 32 + kk];
            float b[12];
            #pragma unroll
            for (int j4 = 0; j4 < 3; ++j4) {
                float4 bb = *(const float4*)&wt[kk * 192 + tx * 12 + j4 * 4];
                b[j4 * 4] = bb.x; b[j4 * 4 + 1] = bb.y;
                b[j4 * 4 + 2] = bb.z; b[j4 * 4 + 3] = bb.w;
            }
            #pragma unroll
            for (int i = 0; i < 4; ++i)
                #pragma unroll
                for (int j = 0; j < 12; ++j)
                    acc[i][j] = fmaf(a[i], b[j], acc[i][j]);
        }
    }

    float bo[12];
    #pragma unroll
    for (int j4 = 0; j4 < 3; ++j4) {
        float4 bb = *(const float4*)&b_out[tx * 12 + j4 * 4];
        bo[j4 * 4] = bb.x; bo[j4 * 4 + 1] = bb.y;
        bo[j4 * 4 + 2] = bb.z; bo[j4 * 4 + 3] = bb.w;
    }
    #pragma unroll
    for (int i = 0; i < 4; ++i) {
        size_t r = row0 + ty * 4 + i;
        #pragma unroll
        for (int j4 = 0; j4 < 3; ++j4) {
            float4 o;
            o.x = acc[i][j4 * 4]     + bo[j4 * 4];
            o.y = acc[i][j4 * 4 + 1] + bo[j4 * 4 + 1];
            o.z = acc[i][j4 * 4 + 2] + bo[j4 * 4 + 2];
            o.w = acc[i][j4 * 4 + 3] + bo[j4 * 4 + 3];
            *(float4*)&io[r * DIM + tx * 12 + j4 * 4] = o;
        }
    }
}

// ===========================================================================
extern "C" void kernel_launch(void* const* d_in, const int* in_sizes, int n_in,
                              void* d_out, int out_size, void* d_ws, size_t ws_size,
                              hipStream_t stream) {
    const float* x          = (const float*)d_in[0];
    const int*   mask       = (const int*)d_in[1];
    const int*   rel_index  = (const int*)d_in[2];
    const float* w_qkv      = (const float*)d_in[3];
    const float* b_qkv      = (const float*)d_in[4];
    const float* w_out      = (const float*)d_in[5];
    const float* b_out      = (const float*)d_in[6];
    const float* bias_table = (const float*)d_in[7];
    float* out = (float*)d_out;

    // ws layout (bytes):
    //   bias_pre @0        : 497664
    //   wq_h     @497664   : 221184   (frag layout)
    //   wq_l     @718848   : 221184
    //   wo_h     @940032   :  73728   (frag layout)
    //   wo_l     @1013760  :  73728   -> total 1087488
    const size_t WS_NEED = 1087488;

    if (ws_size >= WS_NEED) {
        char* ws = (char*)d_ws;
        float*          bias_pre = (float*)ws;
        unsigned short* wq_h     = (unsigned short*)(ws + 497664);
        unsigned short* wq_l     = (unsigned short*)(ws + 718848);
        unsigned short* wo_h     = (unsigned short*)(ws + 940032);
        unsigned short* wo_l     = (unsigned short*)(ws + 1013760);

        hipLaunchKernelGGL(prep_bias, dim3(486), dim3(256), 0, stream,
                           rel_index, bias_table, bias_pre);
        hipLaunchKernelGGL(prep_wq_frag, dim3(432), dim3(256), 0, stream,
                           w_qkv, wq_h, wq_l);
        hipLaunchKernelGGL(prep_wo_frag, dim3(144), dim3(256), 0, stream,
                           w_out, wo_h, wo_l);
        hipLaunchKernelGGL(fused, dim3(NW), dim3(768), 0, stream,
                           x, mask, bias_pre, wq_h, wq_l, b_qkv,
                           wo_h, wo_l, b_out, out);
    } else {
        hipLaunchKernelGGL(attn_kernel, dim3(NW * NH), dim3(256), 0, stream,
                           x, mask, rel_index, w_qkv, b_qkv, bias_table, out);
        hipLaunchKernelGGL(proj_kernel, dim3(NW * NT / 64), dim3(256), 0, stream,
                           out, w_out, b_out);
    }
}